// Round 1
// baseline (474.754 us; speedup 1.0000x reference)
//
#include <hip/hip_runtime.h>
#include <cstdint>
#include <cstddef>

// B=16, N=512, D=768, H=8, F=96;  M = B*N = 8192; GEMM N-cols = 768(h) + 768(gate) = 1536; K = 768
typedef __attribute__((ext_vector_type(4))) float f32x4;
typedef __attribute__((ext_vector_type(8))) __bf16 bf16x8;
typedef __attribute__((ext_vector_type(8))) unsigned short u16x8;

__device__ __forceinline__ unsigned short f2bf(float f){
  unsigned int u = __float_as_uint(f);
  u += 0x7fffu + ((u >> 16) & 1u);          // RNE
  return (unsigned short)(u >> 16);
}

__device__ __forceinline__ void gload_lds16(const void* g, void* l){
  __builtin_amdgcn_global_load_lds((const __attribute__((address_space(1))) void*)g,
                                   (__attribute__((address_space(3))) void*)l, 16, 0, 0);
}

__device__ __forceinline__ f32x4 mfma16(bf16x8 a, bf16x8 b, f32x4 c){
  return __builtin_amdgcn_mfma_f32_16x16x32_bf16(a, b, c, 0, 0, 0);
}

// ---------------- fp32 -> bf16 vector convert ----------------
__global__ __launch_bounds__(256) void f2b_kernel(const float* __restrict__ in,
                                                  unsigned short* __restrict__ out, int n4){
  int i = blockIdx.x * 256 + threadIdx.x;
  if (i >= n4) return;
  f32x4 v = ((const f32x4*)in)[i];
  union { unsigned short u[4]; unsigned long long ll; } o;
  #pragma unroll
  for (int e = 0; e < 4; ++e) o.u[e] = f2bf(v[e]);
  ((unsigned long long*)out)[i] = o.ll;
}

// ---------------- build B^T (K-contiguous) weight matrix: rows 0..767 = Wcat col, 768..1535 = Hw row ----------------
__global__ __launch_bounds__(192) void buildBt_kernel(const float* __restrict__ W,   // [H][D][F]
                                                      const float* __restrict__ Hw,  // [D][D]
                                                      unsigned short* __restrict__ Bt){ // [1536][768]
  int n  = blockIdx.x;        // 0..1535
  int k4 = threadIdx.x;       // 0..191
  float v[4];
  if (n < 768){
    int head = n / 96, f = n % 96;
    const float* base = W + (size_t)head * 768 * 96 + f;
    #pragma unroll
    for (int e = 0; e < 4; ++e) v[e] = base[(size_t)(k4 * 4 + e) * 96];
  } else {
    f32x4 t = *(const f32x4*)(Hw + (size_t)(n - 768) * 768 + k4 * 4);
    #pragma unroll
    for (int e = 0; e < 4; ++e) v[e] = t[e];
  }
  union { unsigned short u[4]; unsigned long long ll; } o;
  #pragma unroll
  for (int e = 0; e < 4; ++e) o.u[e] = f2bf(v[e]);
  ((unsigned long long*)(Bt + (size_t)n * 768))[k4] = o.ll;
}

// ---------------- fused GEMM: C[8192][1536] = A[8192][768] * Bt^T ----------------
// n<768  -> h (fp32 [m][n]) + hT (bf16 [b*8+head][f][node]) for attention V
// n>=768 -> gate logits (fp32 [m][n-768])
__device__ __forceinline__ void stage_tile(const unsigned short* __restrict__ A,
                                           const unsigned short* __restrict__ Bt,
                                           int m0, int n0, int k0, int wid, int lane, char* base){
  #pragma unroll
  for (int c = 0; c < 2; ++c){
    const int u = (wid * 2 + c) * 64 + lane;
    const int row = u >> 2, slot = u & 3;
    const int sw = ((slot ^ (row & 3)) << 3);   // source-side XOR swizzle (linear LDS dest)
    gload_lds16(A  + (size_t)(m0 + row) * 768 + k0 + sw, base +        (wid * 2 + c) * 1024);
    gload_lds16(Bt + (size_t)(n0 + row) * 768 + k0 + sw, base + 8192 + (wid * 2 + c) * 1024);
  }
}

__global__ __launch_bounds__(256, 2)
void gemm_kernel(const unsigned short* __restrict__ A,
                 const unsigned short* __restrict__ Bt,
                 float* __restrict__ hbuf,
                 unsigned short* __restrict__ hT,
                 float* __restrict__ glogit){
  __shared__ __align__(16) char lds[32768];   // 2 bufs * (A 8KB + B 8KB)
  const int tid  = threadIdx.x;
  const int wid  = tid >> 6;
  const int lane = tid & 63;
  const int ntile = blockIdx.x % 12;
  const int mtile = blockIdx.x / 12;
  const int m0 = mtile * 128, n0 = ntile * 128;
  const int wm = (wid >> 1) * 64, wn = (wid & 1) * 64;
  const int g = lane >> 4, r16 = lane & 15;

  f32x4 acc[4][4];
  #pragma unroll
  for (int i = 0; i < 4; ++i)
    #pragma unroll
    for (int j = 0; j < 4; ++j) acc[i][j] = (f32x4){0.f, 0.f, 0.f, 0.f};

  stage_tile(A, Bt, m0, n0, 0, wid, lane, lds);
  __syncthreads();

  for (int kt = 0; kt < 24; ++kt){
    const int cur = kt & 1;
    if (kt < 23) stage_tile(A, Bt, m0, n0, (kt + 1) * 32, wid, lane, lds + (cur ^ 1) * 16384);
    const char* base = lds + cur * 16384;
    bf16x8 af[4], bfr[4];
    #pragma unroll
    for (int t = 0; t < 4; ++t){
      int rowA = wm + t * 16 + r16;
      af[t]  = *(const bf16x8*)(base + rowA * 64 + ((g ^ (rowA & 3)) << 4));
      int rowB = wn + t * 16 + r16;
      bfr[t] = *(const bf16x8*)(base + 8192 + rowB * 64 + ((g ^ (rowB & 3)) << 4));
    }
    #pragma unroll
    for (int mt = 0; mt < 4; ++mt)
      #pragma unroll
      for (int nt = 0; nt < 4; ++nt)
        acc[mt][nt] = mfma16(af[mt], bfr[nt], acc[mt][nt]);
    __syncthreads();
  }

  #pragma unroll
  for (int mt = 0; mt < 4; ++mt){
    #pragma unroll
    for (int nt = 0; nt < 4; ++nt){
      const int n = n0 + wn + nt * 16 + r16;
      #pragma unroll
      for (int r = 0; r < 4; ++r){
        const int m = m0 + wm + mt * 16 + g * 4 + r;
        const float v = acc[mt][nt][r];
        if (n < 768){
          hbuf[(size_t)m * 768 + n] = v;
          const int b = m >> 9, node = m & 511;
          const int head = n / 96, f = n % 96;
          hT[(((size_t)(b * 8 + head)) * 96 + f) * 512 + node] = f2bf(v);
        } else {
          glogit[(size_t)m * 768 + (n - 768)] = v;
        }
      }
    }
  }
}

// ---------------- s/d projections: s[bh][node] = sum_f tanh(h)*a_src ----------------
__global__ __launch_bounds__(256)
void sd_kernel(const float* __restrict__ h, const float* __restrict__ asrc,
               const float* __restrict__ adst, float* __restrict__ s, float* __restrict__ d){
  const int idx  = blockIdx.x * 4 + (threadIdx.x >> 6);   // (m,head): idx = m*8+head
  const int lane = threadIdx.x & 63;
  const int m = idx >> 3, head = idx & 7;
  const float* hr  = h + (size_t)m * 768 + head * 96;
  const float* as_ = asrc + head * 96;
  const float* ad_ = adst + head * 96;
  float t1 = tanhf(hr[lane]);
  float ss = t1 * as_[lane];
  float dd = t1 * ad_[lane];
  if (lane < 32){
    float t2 = tanhf(hr[64 + lane]);
    ss += t2 * as_[64 + lane];
    dd += t2 * ad_[64 + lane];
  }
  #pragma unroll
  for (int o = 32; o > 0; o >>= 1){ ss += __shfl_xor(ss, o); dd += __shfl_xor(dd, o); }
  if (lane == 0){
    const int b = m >> 9, node = m & 511;
    const int o = ((b * 8 + head) << 9) + node;
    s[o] = ss; d[o] = dd;
  }
}

// ---------------- fused masked-softmax attention + PV (flash-style, rank-1 scores) ----------------
__global__ __launch_bounds__(256)
void attn_kernel(const float* __restrict__ s, const float* __restrict__ d,
                 const float* __restrict__ adj,     // [B][N][N]
                 const unsigned short* __restrict__ hT,  // [BH][F][N] bf16
                 const float* __restrict__ bias,    // [F]
                 float* __restrict__ att){          // [BH][N][F]
  const int bh = blockIdx.x;          // 0..127
  const int ib = blockIdx.y;          // 0..7
  const int b  = bh >> 3;
  const int tid = threadIdx.x, wid = tid >> 6, lane = tid & 63;
  const int rowbase = ib * 64 + wid * 16;
  const int g = lane >> 4, r16 = lane & 15;
  const int i_lane = rowbase + r16;
  const float* adjrow = adj + ((size_t)b * 512 + i_lane) * 512;
  const float* dv = d + bh * 512;
  const float s_i = s[bh * 512 + i_lane];

  // pass 1a: M = max over valid j of d_j  (lrelu monotone => m_i = lrelu(s_i + M))
  float Mx = -3e38f;
  for (int t = 0; t < 32; ++t){
    const int j0 = t * 16 + g * 4;
    f32x4 a4 = *(const f32x4*)(adjrow + j0);
    f32x4 d4 = *(const f32x4*)(dv + j0);
    #pragma unroll
    for (int e = 0; e < 4; ++e) if (a4[e] > 0.f) Mx = fmaxf(Mx, d4[e]);
  }
  Mx = fmaxf(Mx, __shfl_xor(Mx, 16));
  Mx = fmaxf(Mx, __shfl_xor(Mx, 32));
  const float scm = s_i + Mx;
  const float m_i = scm > 0.f ? scm : 0.2f * scm;

  // pass 1b: denominator
  float L = 0.f;
  for (int t = 0; t < 32; ++t){
    const int j0 = t * 16 + g * 4;
    f32x4 a4 = *(const f32x4*)(adjrow + j0);
    f32x4 d4 = *(const f32x4*)(dv + j0);
    #pragma unroll
    for (int e = 0; e < 4; ++e){
      float sc = s_i + d4[e]; sc = sc > 0.f ? sc : 0.2f * sc;
      L += (a4[e] > 0.f) ? __expf(sc - m_i) : 0.f;
    }
  }
  L += __shfl_xor(L, 16);
  L += __shfl_xor(L, 32);
  const float linv = 1.f / L;
  __shared__ float linv_s[4][16];
  if (lane < 16) linv_s[wid][lane] = linv;

  // pass 2: P (bf16 frags in-register) @ V (from hT) via MFMA
  f32x4 acc2[6];
  #pragma unroll
  for (int ft = 0; ft < 6; ++ft) acc2[ft] = (f32x4){0.f, 0.f, 0.f, 0.f};
  const unsigned short* hTb = hT + (size_t)bh * 96 * 512;
  for (int jt = 0; jt < 16; ++jt){
    const int j8 = jt * 32 + g * 8;
    f32x4 dA = *(const f32x4*)(dv + j8);
    f32x4 dB = *(const f32x4*)(dv + j8 + 4);
    f32x4 aA = *(const f32x4*)(adjrow + j8);
    f32x4 aB = *(const f32x4*)(adjrow + j8 + 4);
    u16x8 pa;
    #pragma unroll
    for (int e = 0; e < 4; ++e){
      float sc = s_i + dA[e]; sc = sc > 0.f ? sc : 0.2f * sc;
      pa[e]     = f2bf((aA[e] > 0.f) ? __expf(sc - m_i) : 0.f);
      float sc2 = s_i + dB[e]; sc2 = sc2 > 0.f ? sc2 : 0.2f * sc2;
      pa[e + 4] = f2bf((aB[e] > 0.f) ? __expf(sc2 - m_i) : 0.f);
    }
    const bf16x8 af = __builtin_bit_cast(bf16x8, pa);
    #pragma unroll
    for (int ft = 0; ft < 6; ++ft){
      bf16x8 vf = *(const bf16x8*)(hTb + (size_t)(ft * 16 + r16) * 512 + j8);
      acc2[ft] = mfma16(af, vf, acc2[ft]);
    }
  }
  __syncthreads();
  float* ob = att + (size_t)bh * 512 * 96;
  #pragma unroll
  for (int ft = 0; ft < 6; ++ft){
    const int f = ft * 16 + r16;
    const float bv = bias[f];
    #pragma unroll
    for (int r = 0; r < 4; ++r){
      const int i = rowbase + g * 4 + r;
      ob[(size_t)i * 96 + f] = acc2[ft][r] * linv_s[wid][g * 4 + r] + bv;
    }
  }
}

// ---------------- gate + elu + residual + torch-faithful scramble ----------------
__global__ __launch_bounds__(256)
void combine_kernel(const float* __restrict__ att, const float* __restrict__ glogit,
                    const float* __restrict__ Hb, const float* __restrict__ x,
                    float* __restrict__ xo, unsigned short* __restrict__ xob, int write_b){
  const int idx = blockIdx.x * 256 + threadIdx.x;   // 0..1572863 (elements/4)
  const int c4 = idx % 192, mn = idx / 192;
  const int cc = c4 * 4;
  const int bb = mn >> 9, nn = mn & 511;
  const int hh = bb >> 1;
  const int bsrc = ((bb & 1) << 3) + (nn >> 6);
  const int node = ((nn & 63) << 3) + cc / 96;
  const int f = cc % 96;
  f32x4 av = *(const f32x4*)(att + (((size_t)(bsrc * 8 + hh) * 512 + node) * 96 + f));
  f32x4 gl = ((const f32x4*)glogit)[idx];
  f32x4 xv = ((const f32x4*)x)[idx];
  f32x4 hb = *(const f32x4*)(Hb + cc);
  f32x4 o;
  #pragma unroll
  for (int e = 0; e < 4; ++e){
    const float gate = 1.f / (1.f + __expf(-(gl[e] + hb[e])));
    const float a = av[e];
    const float eluv = a > 0.f ? a : (__expf(a) - 1.f);
    o[e] = gate * eluv + (1.f - gate) * xv[e];
  }
  ((f32x4*)xo)[idx] = o;
  if (write_b){
    union { unsigned short u[4]; unsigned long long ll; } ob;
    #pragma unroll
    for (int e = 0; e < 4; ++e) ob.u[e] = f2bf(o[e]);
    ((unsigned long long*)xob)[idx] = ob.ll;
  }
}

extern "C" void kernel_launch(void* const* d_in, const int* in_sizes, int n_in,
                              void* d_out, int out_size, void* d_ws, size_t ws_size,
                              hipStream_t stream){
  const float* emb   = (const float*)d_in[0];
  const float* adj   = (const float*)d_in[1];
  const float* W0    = (const float*)d_in[3];
  const float* b0    = (const float*)d_in[4];
  const float* asrc0 = (const float*)d_in[5];
  const float* adst0 = (const float*)d_in[6];
  const float* Hw0   = (const float*)d_in[7];
  const float* Hb0   = (const float*)d_in[8];
  const float* W1    = (const float*)d_in[9];
  const float* b1    = (const float*)d_in[10];
  const float* asrc1 = (const float*)d_in[11];
  const float* adst1 = (const float*)d_in[12];
  const float* Hw1   = (const float*)d_in[13];
  const float* Hb1   = (const float*)d_in[14];

  char* ws = (char*)d_ws;
  size_t off = 0;
  auto alloc = [&](size_t bytes){ void* p = ws + off; off += (bytes + 255) & ~(size_t)255; return p; };
  unsigned short* x0b  = (unsigned short*)alloc(8192ull * 768 * 2);  // also reused as x1 bf16
  unsigned short* Bt0  = (unsigned short*)alloc(1536ull * 768 * 2);
  unsigned short* Bt1  = (unsigned short*)alloc(1536ull * 768 * 2);
  float* hbuf          = (float*)alloc(8192ull * 768 * 4);
  unsigned short* hT   = (unsigned short*)alloc(8192ull * 768 * 2);
  float* glogit        = (float*)alloc(8192ull * 768 * 4);
  float* sbuf          = (float*)alloc(65536ull * 4);
  float* dbuf          = (float*)alloc(65536ull * 4);
  float* att           = (float*)alloc(8192ull * 768 * 4);
  float* x1            = (float*)alloc(8192ull * 768 * 4);
  (void)ws_size; (void)in_sizes; (void)n_in; (void)out_size;

  f2b_kernel<<<6144, 256, 0, stream>>>(emb, x0b, 1572864);
  buildBt_kernel<<<1536, 192, 0, stream>>>(W0, Hw0, Bt0);
  buildBt_kernel<<<1536, 192, 0, stream>>>(W1, Hw1, Bt1);

  // layer 1
  gemm_kernel<<<768, 256, 0, stream>>>(x0b, Bt0, hbuf, hT, glogit);
  sd_kernel<<<16384, 256, 0, stream>>>(hbuf, asrc0, adst0, sbuf, dbuf);
  attn_kernel<<<dim3(128, 8), 256, 0, stream>>>(sbuf, dbuf, adj, hT, b0, att);
  combine_kernel<<<6144, 256, 0, stream>>>(att, glogit, Hb0, emb, x1, x0b, 1);

  // layer 2 (x0b now holds bf16 of x1)
  gemm_kernel<<<768, 256, 0, stream>>>(x0b, Bt1, hbuf, hT, glogit);
  sd_kernel<<<16384, 256, 0, stream>>>(hbuf, asrc1, adst1, sbuf, dbuf);
  attn_kernel<<<dim3(128, 8), 256, 0, stream>>>(sbuf, dbuf, adj, hT, b1, att);
  combine_kernel<<<6144, 256, 0, stream>>>(att, glogit, Hb1, x1, (float*)d_out, x0b, 0);
}

// Round 2
// 372.285 us; speedup vs baseline: 1.2752x; 1.2752x over previous
//
#include <hip/hip_runtime.h>
#include <cstdint>
#include <cstddef>

// B=16, N=512, D=768, H=8, F=96;  M = B*N = 8192; GEMM N-cols = 768(h) + 768(gate) = 1536; K = 768
typedef __attribute__((ext_vector_type(4))) float f32x4;
typedef __attribute__((ext_vector_type(8))) __bf16 bf16x8;
typedef __attribute__((ext_vector_type(8))) unsigned short u16x8;
typedef __attribute__((ext_vector_type(4))) unsigned short u16x4;

__device__ __forceinline__ unsigned short f2bf(float f){
  unsigned int u = __float_as_uint(f);
  u += 0x7fffu + ((u >> 16) & 1u);          // RNE
  return (unsigned short)(u >> 16);
}
__device__ __forceinline__ float bf2f(unsigned short u){
  return __uint_as_float(((unsigned int)u) << 16);
}

__device__ __forceinline__ void gload_lds16(const void* g, void* l){
  __builtin_amdgcn_global_load_lds((const __attribute__((address_space(1))) void*)g,
                                   (__attribute__((address_space(3))) void*)l, 16, 0, 0);
}

__device__ __forceinline__ f32x4 mfma16(bf16x8 a, bf16x8 b, f32x4 c){
  return __builtin_amdgcn_mfma_f32_16x16x32_bf16(a, b, c, 0, 0, 0);
}

// ---------------- fp32 -> bf16 vector convert ----------------
__global__ __launch_bounds__(256) void f2b_kernel(const float* __restrict__ in,
                                                  unsigned short* __restrict__ out, int n4){
  int i = blockIdx.x * 256 + threadIdx.x;
  if (i >= n4) return;
  f32x4 v = ((const f32x4*)in)[i];
  union { unsigned short u[4]; unsigned long long ll; } o;
  #pragma unroll
  for (int e = 0; e < 4; ++e) o.u[e] = f2bf(v[e]);
  ((unsigned long long*)out)[i] = o.ll;
}

// ---------------- adjacency -> bitmask: mask[b][i][w] bit j = adj[b][i][w*32+j] > 0 ----------------
__global__ __launch_bounds__(256) void mask_kernel(const float* __restrict__ adj,
                                                   unsigned int* __restrict__ mask){
  int idx = blockIdx.x * 256 + threadIdx.x;   // 16*512*16 = 131072 words
  const float* a = adj + (size_t)idx * 32;
  unsigned int m = 0;
  #pragma unroll
  for (int e = 0; e < 8; ++e){
    f32x4 v = *(const f32x4*)(a + e * 4);
    m |= (v[0] > 0.f ? 1u : 0u) << (e * 4);
    m |= (v[1] > 0.f ? 1u : 0u) << (e * 4 + 1);
    m |= (v[2] > 0.f ? 1u : 0u) << (e * 4 + 2);
    m |= (v[3] > 0.f ? 1u : 0u) << (e * 4 + 3);
  }
  mask[idx] = m;
}

// ---------------- build B^T (K-contiguous) weight matrix: rows 0..767 = Wcat col, 768..1535 = Hw row ----------------
__global__ __launch_bounds__(192) void buildBt_kernel(const float* __restrict__ W,   // [H][D][F]
                                                      const float* __restrict__ Hw,  // [D][D]
                                                      unsigned short* __restrict__ Bt){ // [1536][768]
  int n  = blockIdx.x;        // 0..1535
  int k4 = threadIdx.x;       // 0..191
  float v[4];
  if (n < 768){
    int head = n / 96, f = n % 96;
    const float* base = W + (size_t)head * 768 * 96 + f;
    #pragma unroll
    for (int e = 0; e < 4; ++e) v[e] = base[(size_t)(k4 * 4 + e) * 96];
  } else {
    f32x4 t = *(const f32x4*)(Hw + (size_t)(n - 768) * 768 + k4 * 4);
    #pragma unroll
    for (int e = 0; e < 4; ++e) v[e] = t[e];
  }
  union { unsigned short u[4]; unsigned long long ll; } o;
  #pragma unroll
  for (int e = 0; e < 4; ++e) o.u[e] = f2bf(v[e]);
  ((unsigned long long*)(Bt + (size_t)n * 768))[k4] = o.ll;
}

// ---------------- fused GEMM: C[8192][1536] = A[8192][768] * Bt^T ----------------
__device__ __forceinline__ void stage_tile(const unsigned short* __restrict__ A,
                                           const unsigned short* __restrict__ Bt,
                                           int m0, int n0, int k0, int wid, int lane, char* base){
  #pragma unroll
  for (int c = 0; c < 2; ++c){
    const int u = (wid * 2 + c) * 64 + lane;
    const int row = u >> 2, slot = u & 3;
    const int sw = ((slot ^ (row & 3)) << 3);   // source-side XOR swizzle (linear LDS dest)
    gload_lds16(A  + (size_t)(m0 + row) * 768 + k0 + sw, base +        (wid * 2 + c) * 1024);
    gload_lds16(Bt + (size_t)(n0 + row) * 768 + k0 + sw, base + 8192 + (wid * 2 + c) * 1024);
  }
}

__global__ __launch_bounds__(256, 2)
void gemm_kernel(const unsigned short* __restrict__ A,
                 const unsigned short* __restrict__ Bt,
                 float* __restrict__ hbuf,
                 unsigned short* __restrict__ hT,
                 unsigned short* __restrict__ glogit){
  __shared__ __align__(16) char lds[32768];   // 2 bufs * (A 8KB + B 8KB)
  const int tid  = threadIdx.x;
  const int wid  = tid >> 6;
  const int lane = tid & 63;
  const int ntile = blockIdx.x % 12;
  const int mtile = blockIdx.x / 12;
  const int m0 = mtile * 128, n0 = ntile * 128;
  const int wm = (wid >> 1) * 64, wn = (wid & 1) * 64;
  const int g = lane >> 4, r16 = lane & 15;

  f32x4 acc[4][4];
  #pragma unroll
  for (int i = 0; i < 4; ++i)
    #pragma unroll
    for (int j = 0; j < 4; ++j) acc[i][j] = (f32x4){0.f, 0.f, 0.f, 0.f};

  stage_tile(A, Bt, m0, n0, 0, wid, lane, lds);
  __syncthreads();

  for (int kt = 0; kt < 24; ++kt){
    const int cur = kt & 1;
    if (kt < 23) stage_tile(A, Bt, m0, n0, (kt + 1) * 32, wid, lane, lds + (cur ^ 1) * 16384);
    const char* base = lds + cur * 16384;
    bf16x8 af[4], bfr[4];
    #pragma unroll
    for (int t = 0; t < 4; ++t){
      int rowA = wm + t * 16 + r16;
      af[t]  = *(const bf16x8*)(base + rowA * 64 + ((g ^ (rowA & 3)) << 4));
      int rowB = wn + t * 16 + r16;
      bfr[t] = *(const bf16x8*)(base + 8192 + rowB * 64 + ((g ^ (rowB & 3)) << 4));
    }
    #pragma unroll
    for (int mt = 0; mt < 4; ++mt)
      #pragma unroll
      for (int nt = 0; nt < 4; ++nt)
        acc[mt][nt] = mfma16(af[mt], bfr[nt], acc[mt][nt]);
    __syncthreads();
  }

  if (n0 < 768){
    #pragma unroll
    for (int mt = 0; mt < 4; ++mt){
      #pragma unroll
      for (int nt = 0; nt < 4; ++nt){
        const int n = n0 + wn + nt * 16 + r16;
        const int head = n / 96, f = n % 96;
        #pragma unroll
        for (int r = 0; r < 4; ++r){
          const int m = m0 + wm + mt * 16 + g * 4 + r;
          const float v = acc[mt][nt][r];
          hbuf[(size_t)m * 768 + n] = v;
          const int b = m >> 9, node = m & 511;
          hT[(((size_t)(b * 8 + head)) * 96 + f) * 512 + node] = f2bf(v);
        }
      }
    }
  } else {
    #pragma unroll
    for (int mt = 0; mt < 4; ++mt){
      #pragma unroll
      for (int nt = 0; nt < 4; ++nt){
        const int n = n0 + wn + nt * 16 + r16;
        #pragma unroll
        for (int r = 0; r < 4; ++r){
          const int m = m0 + wm + mt * 16 + g * 4 + r;
          glogit[(size_t)m * 768 + (n - 768)] = f2bf(acc[mt][nt][r]);
        }
      }
    }
  }
}

// ---------------- s/d projections: s[bh][node] = sum_f tanh(h)*a_src ----------------
__global__ __launch_bounds__(256)
void sd_kernel(const float* __restrict__ h, const float* __restrict__ asrc,
               const float* __restrict__ adst, float* __restrict__ s, float* __restrict__ d){
  const int idx  = blockIdx.x * 4 + (threadIdx.x >> 6);   // (m,head): idx = m*8+head
  const int lane = threadIdx.x & 63;
  const int m = idx >> 3, head = idx & 7;
  const float* hr  = h + (size_t)m * 768 + head * 96;
  const float* as_ = asrc + head * 96;
  const float* ad_ = adst + head * 96;
  float t1 = tanhf(hr[lane]);
  float ss = t1 * as_[lane];
  float dd = t1 * ad_[lane];
  if (lane < 32){
    float t2 = tanhf(hr[64 + lane]);
    ss += t2 * as_[64 + lane];
    dd += t2 * ad_[64 + lane];
  }
  #pragma unroll
  for (int o = 32; o > 0; o >>= 1){ ss += __shfl_xor(ss, o); dd += __shfl_xor(dd, o); }
  if (lane == 0){
    const int b = m >> 9, node = m & 511;
    const int o = ((b * 8 + head) << 9) + node;
    s[o] = ss; d[o] = dd;
  }
}

// ---------------- fused masked-softmax attention + PV (single j-sweep, bitmask, fused denominator) ----------------
__global__ __launch_bounds__(256)
void attn_kernel(const float* __restrict__ s, const float* __restrict__ d,
                 const unsigned int* __restrict__ mask,   // [B][512][16]
                 const unsigned short* __restrict__ hT,   // [BH][F][N] bf16
                 const float* __restrict__ bias,          // [F]
                 float* __restrict__ att){                // [BH][N][F]
  const int idx = blockIdx.x;           // 0..1023 ; bh = idx&127 keeps same-bh blocks on one XCD
  const int bh = idx & 127, ib = idx >> 7;
  const int b  = bh >> 3;
  const int tid = threadIdx.x, wid = tid >> 6, lane = tid & 63;
  const int g = lane >> 4, r16 = lane & 15;
  const int rowbase = ib * 64 + wid * 16;

  __shared__ float d_lds[512];
  const float* dv = d + bh * 512;
  if (tid < 128) ((f32x4*)d_lds)[tid] = ((const f32x4*)dv)[tid];
  __syncthreads();

  // per-bh UNMASKED max of d: valid upper bound since lrelu is monotone; row-independent
  float Mx = d_lds[lane];
  #pragma unroll
  for (int t = 1; t < 8; ++t) Mx = fmaxf(Mx, d_lds[t * 64 + lane]);
  #pragma unroll
  for (int o = 32; o > 0; o >>= 1) Mx = fmaxf(Mx, __shfl_xor(Mx, o));

  const int i_mine = rowbase + r16;     // this lane's P-row
  const float s_i = s[bh * 512 + i_mine];
  const float scm = s_i + Mx;
  const float m_i = fmaxf(scm, 0.2f * scm);

  unsigned int mw[16];
  {
    const uint4* mrow = (const uint4*)(mask + ((size_t)b * 512 + i_mine) * 16);
    uint4 a0 = mrow[0], a1 = mrow[1], a2 = mrow[2], a3 = mrow[3];
    mw[0]=a0.x; mw[1]=a0.y; mw[2]=a0.z; mw[3]=a0.w;
    mw[4]=a1.x; mw[5]=a1.y; mw[6]=a1.z; mw[7]=a1.w;
    mw[8]=a2.x; mw[9]=a2.y; mw[10]=a2.z; mw[11]=a2.w;
    mw[12]=a3.x; mw[13]=a3.y; mw[14]=a3.z; mw[15]=a3.w;
  }

  f32x4 acc2[6];
  #pragma unroll
  for (int ft = 0; ft < 6; ++ft) acc2[ft] = (f32x4){0.f, 0.f, 0.f, 0.f};
  float L = 0.f;
  const unsigned short* hTb = hT + (size_t)bh * 96 * 512;

  #pragma unroll
  for (int jt = 0; jt < 16; ++jt){
    const unsigned int w = mw[jt];
    const int j8 = jt * 32 + g * 8;     // this lane's A-frag k-slice
    f32x4 dA = *(const f32x4*)(d_lds + j8);
    f32x4 dB = *(const f32x4*)(d_lds + j8 + 4);
    u16x8 pa;
    #pragma unroll
    for (int e = 0; e < 4; ++e){
      float sc = s_i + dA[e]; sc = fmaxf(sc, 0.2f * sc);
      float p = ((w >> (g * 8 + e)) & 1u) ? __expf(sc - m_i) : 0.f;
      L += p; pa[e] = f2bf(p);
      float sc2 = s_i + dB[e]; sc2 = fmaxf(sc2, 0.2f * sc2);
      float p2 = ((w >> (g * 8 + 4 + e)) & 1u) ? __expf(sc2 - m_i) : 0.f;
      L += p2; pa[4 + e] = f2bf(p2);
    }
    const bf16x8 af = __builtin_bit_cast(bf16x8, pa);
    #pragma unroll
    for (int ft = 0; ft < 6; ++ft){
      bf16x8 vf = *(const bf16x8*)(hTb + (size_t)(ft * 16 + r16) * 512 + j8);
      acc2[ft] = mfma16(af, vf, acc2[ft]);
    }
  }

  // denominator: reduce this row's partial sums across the 4 k-groups
  L += __shfl_xor(L, 16);
  L += __shfl_xor(L, 32);
  const float linv = 1.f / L;
  float lr[4];
  #pragma unroll
  for (int r = 0; r < 4; ++r) lr[r] = __shfl(linv, g * 4 + r);  // linv of output row rowbase+g*4+r

  float* ob = att + (size_t)bh * 512 * 96;
  #pragma unroll
  for (int ft = 0; ft < 6; ++ft){
    const int f = ft * 16 + r16;
    const float bv = bias[f];
    #pragma unroll
    for (int r = 0; r < 4; ++r)
      ob[(size_t)(rowbase + g * 4 + r) * 96 + f] = acc2[ft][r] * lr[r] + bv;
  }
}

// ---------------- gate + elu + residual + torch-faithful scramble ----------------
__global__ __launch_bounds__(256)
void combine_kernel(const float* __restrict__ att, const unsigned short* __restrict__ glogit,
                    const float* __restrict__ Hb, const float* __restrict__ x,
                    float* __restrict__ xo, unsigned short* __restrict__ xob, int write_b){
  const int idx = blockIdx.x * 256 + threadIdx.x;   // 0..1572863 (elements/4)
  const int c4 = idx % 192, mn = idx / 192;
  const int cc = c4 * 4;
  const int bb = mn >> 9, nn = mn & 511;
  const int hh = bb >> 1;
  const int bsrc = ((bb & 1) << 3) + (nn >> 6);
  const int node = ((nn & 63) << 3) + cc / 96;
  const int f = cc % 96;
  f32x4 av = *(const f32x4*)(att + (((size_t)(bsrc * 8 + hh) * 512 + node) * 96 + f));
  u16x4 gl = ((const u16x4*)glogit)[idx];
  f32x4 xv = ((const f32x4*)x)[idx];
  f32x4 hb = *(const f32x4*)(Hb + cc);
  f32x4 o;
  #pragma unroll
  for (int e = 0; e < 4; ++e){
    const float gate = 1.f / (1.f + __expf(-(bf2f(gl[e]) + hb[e])));
    const float a = av[e];
    const float eluv = a > 0.f ? a : (__expf(a) - 1.f);
    o[e] = gate * eluv + (1.f - gate) * xv[e];
  }
  ((f32x4*)xo)[idx] = o;
  if (write_b){
    union { unsigned short u[4]; unsigned long long ll; } ob;
    #pragma unroll
    for (int e = 0; e < 4; ++e) ob.u[e] = f2bf(o[e]);
    ((unsigned long long*)xob)[idx] = ob.ll;
  }
}

extern "C" void kernel_launch(void* const* d_in, const int* in_sizes, int n_in,
                              void* d_out, int out_size, void* d_ws, size_t ws_size,
                              hipStream_t stream){
  const float* emb   = (const float*)d_in[0];
  const float* adj   = (const float*)d_in[1];
  const float* W0    = (const float*)d_in[3];
  const float* b0    = (const float*)d_in[4];
  const float* asrc0 = (const float*)d_in[5];
  const float* adst0 = (const float*)d_in[6];
  const float* Hw0   = (const float*)d_in[7];
  const float* Hb0   = (const float*)d_in[8];
  const float* W1    = (const float*)d_in[9];
  const float* b1    = (const float*)d_in[10];
  const float* asrc1 = (const float*)d_in[11];
  const float* adst1 = (const float*)d_in[12];
  const float* Hw1   = (const float*)d_in[13];
  const float* Hb1   = (const float*)d_in[14];

  char* ws = (char*)d_ws;
  size_t off = 0;
  auto alloc = [&](size_t bytes){ void* p = ws + off; off += (bytes + 255) & ~(size_t)255; return p; };
  unsigned short* x0b  = (unsigned short*)alloc(8192ull * 768 * 2);  // also reused as x1 bf16
  unsigned short* Bt0  = (unsigned short*)alloc(1536ull * 768 * 2);
  unsigned short* Bt1  = (unsigned short*)alloc(1536ull * 768 * 2);
  float* hbuf          = (float*)alloc(8192ull * 768 * 4);
  unsigned short* hT   = (unsigned short*)alloc(8192ull * 768 * 2);
  unsigned short* glogit = (unsigned short*)alloc(8192ull * 768 * 2);
  float* sbuf          = (float*)alloc(65536ull * 4);
  float* dbuf          = (float*)alloc(65536ull * 4);
  float* att           = (float*)alloc(8192ull * 768 * 4);
  float* x1            = (float*)alloc(8192ull * 768 * 4);
  unsigned int* mask   = (unsigned int*)alloc(16ull * 512 * 16 * 4);
  (void)ws_size; (void)in_sizes; (void)n_in; (void)out_size;

  f2b_kernel<<<6144, 256, 0, stream>>>(emb, x0b, 1572864);
  mask_kernel<<<512, 256, 0, stream>>>(adj, mask);
  buildBt_kernel<<<1536, 192, 0, stream>>>(W0, Hw0, Bt0);
  buildBt_kernel<<<1536, 192, 0, stream>>>(W1, Hw1, Bt1);

  // layer 1
  gemm_kernel<<<768, 256, 0, stream>>>(x0b, Bt0, hbuf, hT, glogit);
  sd_kernel<<<16384, 256, 0, stream>>>(hbuf, asrc0, adst0, sbuf, dbuf);
  attn_kernel<<<1024, 256, 0, stream>>>(sbuf, dbuf, mask, hT, b0, att);
  combine_kernel<<<6144, 256, 0, stream>>>(att, glogit, Hb0, emb, x1, x0b, 1);

  // layer 2 (x0b now holds bf16 of x1)
  gemm_kernel<<<768, 256, 0, stream>>>(x0b, Bt1, hbuf, hT, glogit);
  sd_kernel<<<16384, 256, 0, stream>>>(hbuf, asrc1, adst1, sbuf, dbuf);
  attn_kernel<<<1024, 256, 0, stream>>>(sbuf, dbuf, mask, hT, b1, att);
  combine_kernel<<<6144, 256, 0, stream>>>(att, glogit, Hb1, x1, (float*)d_out, x0b, 0);
}

// Round 3
// 319.436 us; speedup vs baseline: 1.4862x; 1.1654x over previous
//
#include <hip/hip_runtime.h>
#include <cstdint>
#include <cstddef>

// B=16, N=512, D=768, H=8, F=96;  M = B*N = 8192; GEMM N-cols = 768(h) + 768(gate) = 1536; K = 768
typedef __attribute__((ext_vector_type(4))) float f32x4;
typedef __attribute__((ext_vector_type(8))) __bf16 bf16x8;
typedef __attribute__((ext_vector_type(8))) unsigned short u16x8;
typedef __attribute__((ext_vector_type(4))) unsigned short u16x4;

__device__ __forceinline__ unsigned short f2bf(float f){
  unsigned int u = __float_as_uint(f);
  u += 0x7fffu + ((u >> 16) & 1u);          // RNE
  return (unsigned short)(u >> 16);
}
__device__ __forceinline__ float bf2f(unsigned short u){
  return __uint_as_float(((unsigned int)u) << 16);
}

__device__ __forceinline__ void gload_lds16(const void* g, void* l){
  __builtin_amdgcn_global_load_lds((const __attribute__((address_space(1))) void*)g,
                                   (__attribute__((address_space(3))) void*)l, 16, 0, 0);
}

__device__ __forceinline__ f32x4 mfma16(bf16x8 a, bf16x8 b, f32x4 c){
  return __builtin_amdgcn_mfma_f32_16x16x32_bf16(a, b, c, 0, 0, 0);
}

// ---------------- fp32 -> bf16 vector convert ----------------
__global__ __launch_bounds__(256) void f2b_kernel(const float* __restrict__ in,
                                                  unsigned short* __restrict__ out, int n4){
  int i = blockIdx.x * 256 + threadIdx.x;
  if (i >= n4) return;
  f32x4 v = ((const f32x4*)in)[i];
  union { unsigned short u[4]; unsigned long long ll; } o;
  #pragma unroll
  for (int e = 0; e < 4; ++e) o.u[e] = f2bf(v[e]);
  ((unsigned long long*)out)[i] = o.ll;
}

// ---------------- adjacency -> bitmask: mask[b][i][w] bit j = adj[b][i][w*32+j] > 0 ----------------
__global__ __launch_bounds__(256) void mask_kernel(const float* __restrict__ adj,
                                                   unsigned int* __restrict__ mask){
  int idx = blockIdx.x * 256 + threadIdx.x;   // 16*512*16 = 131072 words
  const float* a = adj + (size_t)idx * 32;
  unsigned int m = 0;
  #pragma unroll
  for (int e = 0; e < 8; ++e){
    f32x4 v = *(const f32x4*)(a + e * 4);
    m |= (v[0] > 0.f ? 1u : 0u) << (e * 4);
    m |= (v[1] > 0.f ? 1u : 0u) << (e * 4 + 1);
    m |= (v[2] > 0.f ? 1u : 0u) << (e * 4 + 2);
    m |= (v[3] > 0.f ? 1u : 0u) << (e * 4 + 3);
  }
  mask[idx] = m;
}

// ---------------- build B^T (K-contiguous) weight matrix: rows 0..767 = Wcat col, 768..1535 = Hw row ----------------
__global__ __launch_bounds__(192) void buildBt_kernel(const float* __restrict__ W,   // [H][D][F]
                                                      const float* __restrict__ Hw,  // [D][D]
                                                      unsigned short* __restrict__ Bt){ // [1536][768]
  int n  = blockIdx.x;        // 0..1535
  int k4 = threadIdx.x;       // 0..191
  float v[4];
  if (n < 768){
    int head = n / 96, f = n % 96;
    const float* base = W + (size_t)head * 768 * 96 + f;
    #pragma unroll
    for (int e = 0; e < 4; ++e) v[e] = base[(size_t)(k4 * 4 + e) * 96];
  } else {
    f32x4 t = *(const f32x4*)(Hw + (size_t)(n - 768) * 768 + k4 * 4);
    #pragma unroll
    for (int e = 0; e < 4; ++e) v[e] = t[e];
  }
  union { unsigned short u[4]; unsigned long long ll; } o;
  #pragma unroll
  for (int e = 0; e < 4; ++e) o.u[e] = f2bf(v[e]);
  ((unsigned long long*)(Bt + (size_t)n * 768))[k4] = o.ll;
}

// ---------------- fused GEMM: C[8192][1536] = A[8192][768] * Bt^T ----------------
__device__ __forceinline__ void stage_tile(const unsigned short* __restrict__ A,
                                           const unsigned short* __restrict__ Bt,
                                           int m0, int n0, int k0, int wid, int lane, char* base){
  #pragma unroll
  for (int c = 0; c < 2; ++c){
    const int u = (wid * 2 + c) * 64 + lane;
    const int row = u >> 2, slot = u & 3;
    const int sw = ((slot ^ (row & 3)) << 3);   // source-side XOR swizzle (linear LDS dest)
    gload_lds16(A  + (size_t)(m0 + row) * 768 + k0 + sw, base +        (wid * 2 + c) * 1024);
    gload_lds16(Bt + (size_t)(n0 + row) * 768 + k0 + sw, base + 8192 + (wid * 2 + c) * 1024);
  }
}

__global__ __launch_bounds__(256, 2)
void gemm_kernel(const unsigned short* __restrict__ A,
                 const unsigned short* __restrict__ Bt,
                 float* __restrict__ hbuf,
                 unsigned short* __restrict__ hT,
                 unsigned short* __restrict__ glogit){
  __shared__ __align__(16) char lds[32768];   // 2 bufs * (A 8KB + B 8KB)
  const int tid  = threadIdx.x;
  const int wid  = tid >> 6;
  const int lane = tid & 63;
  const int ntile = blockIdx.x % 12;
  const int mtile = blockIdx.x / 12;
  const int m0 = mtile * 128, n0 = ntile * 128;
  const int wm = (wid >> 1) * 64, wn = (wid & 1) * 64;
  const int g = lane >> 4, r16 = lane & 15;

  f32x4 acc[4][4];
  #pragma unroll
  for (int i = 0; i < 4; ++i)
    #pragma unroll
    for (int j = 0; j < 4; ++j) acc[i][j] = (f32x4){0.f, 0.f, 0.f, 0.f};

  stage_tile(A, Bt, m0, n0, 0, wid, lane, lds);
  __syncthreads();

  for (int kt = 0; kt < 24; ++kt){
    const int cur = kt & 1;
    if (kt < 23) stage_tile(A, Bt, m0, n0, (kt + 1) * 32, wid, lane, lds + (cur ^ 1) * 16384);
    const char* base = lds + cur * 16384;
    bf16x8 af[4], bfr[4];
    #pragma unroll
    for (int t = 0; t < 4; ++t){
      int rowA = wm + t * 16 + r16;
      af[t]  = *(const bf16x8*)(base + rowA * 64 + ((g ^ (rowA & 3)) << 4));
      int rowB = wn + t * 16 + r16;
      bfr[t] = *(const bf16x8*)(base + 8192 + rowB * 64 + ((g ^ (rowB & 3)) << 4));
    }
    #pragma unroll
    for (int mt = 0; mt < 4; ++mt)
      #pragma unroll
      for (int nt = 0; nt < 4; ++nt)
        acc[mt][nt] = mfma16(af[mt], bfr[nt], acc[mt][nt]);
    __syncthreads();
  }

  if (n0 < 768){
    #pragma unroll
    for (int mt = 0; mt < 4; ++mt){
      #pragma unroll
      for (int nt = 0; nt < 4; ++nt){
        const int n = n0 + wn + nt * 16 + r16;
        const int head = n / 96, f = n % 96;
        #pragma unroll
        for (int r = 0; r < 4; ++r){
          const int m = m0 + wm + mt * 16 + g * 4 + r;
          const float v = acc[mt][nt][r];
          hbuf[(size_t)m * 768 + n] = v;
          const int b = m >> 9, node = m & 511;
          hT[(((size_t)(b * 8 + head)) * 96 + f) * 512 + node] = f2bf(v);
        }
      }
    }
  } else {
    #pragma unroll
    for (int mt = 0; mt < 4; ++mt){
      #pragma unroll
      for (int nt = 0; nt < 4; ++nt){
        const int n = n0 + wn + nt * 16 + r16;
        #pragma unroll
        for (int r = 0; r < 4; ++r){
          const int m = m0 + wm + mt * 16 + g * 4 + r;
          glogit[(size_t)m * 768 + (n - 768)] = f2bf(acc[mt][nt][r]);
        }
      }
    }
  }
}

// ---------------- s/d projections: s[bh][node] = sum_f tanh(h)*a_src ----------------
__global__ __launch_bounds__(256)
void sd_kernel(const float* __restrict__ h, const float* __restrict__ asrc,
               const float* __restrict__ adst, float* __restrict__ s, float* __restrict__ d){
  const int idx  = blockIdx.x * 4 + (threadIdx.x >> 6);   // (m,head): idx = m*8+head
  const int lane = threadIdx.x & 63;
  const int m = idx >> 3, head = idx & 7;
  const float* hr  = h + (size_t)m * 768 + head * 96;
  const float* as_ = asrc + head * 96;
  const float* ad_ = adst + head * 96;
  float t1 = tanhf(hr[lane]);
  float ss = t1 * as_[lane];
  float dd = t1 * ad_[lane];
  if (lane < 32){
    float t2 = tanhf(hr[64 + lane]);
    ss += t2 * as_[64 + lane];
    dd += t2 * ad_[64 + lane];
  }
  #pragma unroll
  for (int o = 32; o > 0; o >>= 1){ ss += __shfl_xor(ss, o); dd += __shfl_xor(dd, o); }
  if (lane == 0){
    const int b = m >> 9, node = m & 511;
    const int o = ((b * 8 + head) << 9) + node;
    s[o] = ss; d[o] = dd;
  }
}

// ---------------- fused masked-softmax attention + PV ----------------
// Single j-sweep; V staged in LDS per 64-j pair (double-buffered, source-swizzled
// global_load_lds so ds_read_b128 fragment reads are conflict-free).
__global__ __launch_bounds__(256)
void attn_kernel(const float* __restrict__ s, const float* __restrict__ d,
                 const unsigned int* __restrict__ mask,   // [B][512][16]
                 const unsigned short* __restrict__ hT,   // [BH][F][N] bf16
                 const float* __restrict__ bias,          // [F]
                 float* __restrict__ att){                // [BH][N][F]
  const int idx = blockIdx.x;           // bh = idx&127 keeps same-bh blocks on one XCD
  const int bh = idx & 127, ib = idx >> 7;
  const int b  = bh >> 3;
  const int tid = threadIdx.x, wid = tid >> 6, lane = tid & 63;
  const int g = lane >> 4, r16 = lane & 15;
  const int rowbase = ib * 64 + wid * 16;

  __shared__ float d_lds[512];
  __shared__ __align__(16) char vbuf[2][12288];   // [96 f][8 slots][16B], slot content = slot^(row&7)
  const float* dv = d + bh * 512;
  if (tid < 128) ((f32x4*)d_lds)[tid] = ((const f32x4*)dv)[tid];

  const unsigned short* hTb = hT + (size_t)bh * 96 * 512;

  // stage the 96x64 V slice for j-pair p: 768 chunks of 16B, 3 per thread.
  // linear LDS dest (wave-uniform base + lane*16); XOR swizzle applied on SOURCE.
  auto stage = [&](int p, int bufi){
    #pragma unroll
    for (int ss2 = 0; ss2 < 3; ++ss2){
      const int ch = ss2 * 256 + tid;
      const int row = ch >> 3, slotpos = ch & 7;
      const int cj = slotpos ^ (row & 7);
      gload_lds16(hTb + (size_t)row * 512 + p * 64 + cj * 8, vbuf[bufi] + ch * 16);
    }
  };

  const int i_mine = rowbase + r16;     // this lane's P-row
  const float s_i = s[bh * 512 + i_mine];

  unsigned int mw[16];
  {
    const uint4* mrow = (const uint4*)(mask + ((size_t)b * 512 + i_mine) * 16);
    uint4 a0 = mrow[0], a1 = mrow[1], a2 = mrow[2], a3 = mrow[3];
    mw[0]=a0.x; mw[1]=a0.y; mw[2]=a0.z; mw[3]=a0.w;
    mw[4]=a1.x; mw[5]=a1.y; mw[6]=a1.z; mw[7]=a1.w;
    mw[8]=a2.x; mw[9]=a2.y; mw[10]=a2.z; mw[11]=a2.w;
    mw[12]=a3.x; mw[13]=a3.y; mw[14]=a3.z; mw[15]=a3.w;
  }

  stage(0, 0);
  __syncthreads();   // implicit vmcnt(0) drain: stage(0) + d_lds landed

  // per-bh UNMASKED max of d: valid upper bound since lrelu is monotone
  float Mx = d_lds[lane];
  #pragma unroll
  for (int t = 1; t < 8; ++t) Mx = fmaxf(Mx, d_lds[t * 64 + lane]);
  #pragma unroll
  for (int o = 32; o > 0; o >>= 1) Mx = fmaxf(Mx, __shfl_xor(Mx, o));
  const float scm = s_i + Mx;
  const float m_i = fmaxf(scm, 0.2f * scm);

  f32x4 acc2[6];
  #pragma unroll
  for (int ft = 0; ft < 6; ++ft) acc2[ft] = (f32x4){0.f, 0.f, 0.f, 0.f};
  float L = 0.f;

  for (int p = 0; p < 8; ++p){
    if (p < 7) stage(p + 1, (p + 1) & 1);
    const char* vb = vbuf[p & 1];
    #pragma unroll
    for (int half = 0; half < 2; ++half){
      const int jt = p * 2 + half;
      const unsigned int w = mw[jt];
      const int j8 = jt * 32 + g * 8;
      f32x4 dA = *(const f32x4*)(d_lds + j8);
      f32x4 dB = *(const f32x4*)(d_lds + j8 + 4);
      u16x8 pa;
      #pragma unroll
      for (int e = 0; e < 4; ++e){
        float sc = s_i + dA[e]; sc = fmaxf(sc, 0.2f * sc);
        float p1 = ((w >> (g * 8 + e)) & 1u) ? __expf(sc - m_i) : 0.f;
        L += p1; pa[e] = f2bf(p1);
        float sc2 = s_i + dB[e]; sc2 = fmaxf(sc2, 0.2f * sc2);
        float p2 = ((w >> (g * 8 + 4 + e)) & 1u) ? __expf(sc2 - m_i) : 0.f;
        L += p2; pa[4 + e] = f2bf(p2);
      }
      const bf16x8 af = __builtin_bit_cast(bf16x8, pa);
      const int slot = ((half * 4 + g) ^ (r16 & 7)) * 16;
      #pragma unroll
      for (int ft = 0; ft < 6; ++ft){
        bf16x8 vf = *(const bf16x8*)(vb + (ft * 16 + r16) * 128 + slot);
        acc2[ft] = mfma16(af, vf, acc2[ft]);
      }
    }
    __syncthreads();   // drains stage(p+1); fences buf reuse for p+2
  }

  // denominator: reduce this row's partial sums across the 4 k-groups
  L += __shfl_xor(L, 16);
  L += __shfl_xor(L, 32);
  const float linv = 1.f / L;
  float lr[4];
  #pragma unroll
  for (int r = 0; r < 4; ++r) lr[r] = __shfl(linv, g * 4 + r);  // linv of output row rowbase+g*4+r

  float* ob = att + (size_t)bh * 512 * 96;
  #pragma unroll
  for (int ft = 0; ft < 6; ++ft){
    const int f = ft * 16 + r16;
    const float bv = bias[f];
    #pragma unroll
    for (int r = 0; r < 4; ++r)
      ob[(size_t)(rowbase + g * 4 + r) * 96 + f] = acc2[ft][r] * lr[r] + bv;
  }
}

// ---------------- gate + elu + residual + torch-faithful scramble ----------------
__global__ __launch_bounds__(256)
void combine_kernel(const float* __restrict__ att, const unsigned short* __restrict__ glogit,
                    const float* __restrict__ Hb, const float* __restrict__ x,
                    float* __restrict__ xo, unsigned short* __restrict__ xob, int write_b){
  const int idx = blockIdx.x * 256 + threadIdx.x;   // 0..1572863 (elements/4)
  const int c4 = idx % 192, mn = idx / 192;
  const int cc = c4 * 4;
  const int bb = mn >> 9, nn = mn & 511;
  const int hh = bb >> 1;
  const int bsrc = ((bb & 1) << 3) + (nn >> 6);
  const int node = ((nn & 63) << 3) + cc / 96;
  const int f = cc % 96;
  f32x4 av = *(const f32x4*)(att + (((size_t)(bsrc * 8 + hh) * 512 + node) * 96 + f));
  u16x4 gl = ((const u16x4*)glogit)[idx];
  f32x4 xv = ((const f32x4*)x)[idx];
  f32x4 hb = *(const f32x4*)(Hb + cc);
  f32x4 o;
  #pragma unroll
  for (int e = 0; e < 4; ++e){
    const float gate = 1.f / (1.f + __expf(-(bf2f(gl[e]) + hb[e])));
    const float a = av[e];
    const float eluv = a > 0.f ? a : (__expf(a) - 1.f);
    o[e] = gate * eluv + (1.f - gate) * xv[e];
  }
  ((f32x4*)xo)[idx] = o;
  if (write_b){
    union { unsigned short u[4]; unsigned long long ll; } ob;
    #pragma unroll
    for (int e = 0; e < 4; ++e) ob.u[e] = f2bf(o[e]);
    ((unsigned long long*)xob)[idx] = ob.ll;
  }
}

extern "C" void kernel_launch(void* const* d_in, const int* in_sizes, int n_in,
                              void* d_out, int out_size, void* d_ws, size_t ws_size,
                              hipStream_t stream){
  const float* emb   = (const float*)d_in[0];
  const float* adj   = (const float*)d_in[1];
  const float* W0    = (const float*)d_in[3];
  const float* b0    = (const float*)d_in[4];
  const float* asrc0 = (const float*)d_in[5];
  const float* adst0 = (const float*)d_in[6];
  const float* Hw0   = (const float*)d_in[7];
  const float* Hb0   = (const float*)d_in[8];
  const float* W1    = (const float*)d_in[9];
  const float* b1    = (const float*)d_in[10];
  const float* asrc1 = (const float*)d_in[11];
  const float* adst1 = (const float*)d_in[12];
  const float* Hw1   = (const float*)d_in[13];
  const float* Hb1   = (const float*)d_in[14];

  char* ws = (char*)d_ws;
  size_t off = 0;
  auto alloc = [&](size_t bytes){ void* p = ws + off; off += (bytes + 255) & ~(size_t)255; return p; };
  unsigned short* x0b  = (unsigned short*)alloc(8192ull * 768 * 2);  // also reused as x1 bf16
  unsigned short* Bt0  = (unsigned short*)alloc(1536ull * 768 * 2);
  unsigned short* Bt1  = (unsigned short*)alloc(1536ull * 768 * 2);
  float* hbuf          = (float*)alloc(8192ull * 768 * 4);
  unsigned short* hT   = (unsigned short*)alloc(8192ull * 768 * 2);
  unsigned short* glogit = (unsigned short*)alloc(8192ull * 768 * 2);
  float* sbuf          = (float*)alloc(65536ull * 4);
  float* dbuf          = (float*)alloc(65536ull * 4);
  float* att           = (float*)alloc(8192ull * 768 * 4);
  float* x1            = (float*)alloc(8192ull * 768 * 4);
  unsigned int* mask   = (unsigned int*)alloc(16ull * 512 * 16 * 4);
  (void)ws_size; (void)in_sizes; (void)n_in; (void)out_size;

  f2b_kernel<<<6144, 256, 0, stream>>>(emb, x0b, 1572864);
  mask_kernel<<<512, 256, 0, stream>>>(adj, mask);
  buildBt_kernel<<<1536, 192, 0, stream>>>(W0, Hw0, Bt0);
  buildBt_kernel<<<1536, 192, 0, stream>>>(W1, Hw1, Bt1);

  // layer 1
  gemm_kernel<<<768, 256, 0, stream>>>(x0b, Bt0, hbuf, hT, glogit);
  sd_kernel<<<16384, 256, 0, stream>>>(hbuf, asrc0, adst0, sbuf, dbuf);
  attn_kernel<<<1024, 256, 0, stream>>>(sbuf, dbuf, mask, hT, b0, att);
  combine_kernel<<<6144, 256, 0, stream>>>(att, glogit, Hb0, emb, x1, x0b, 1);

  // layer 2 (x0b now holds bf16 of x1)
  gemm_kernel<<<768, 256, 0, stream>>>(x0b, Bt1, hbuf, hT, glogit);
  sd_kernel<<<16384, 256, 0, stream>>>(hbuf, asrc1, adst1, sbuf, dbuf);
  attn_kernel<<<1024, 256, 0, stream>>>(sbuf, dbuf, mask, hT, b1, att);
  combine_kernel<<<6144, 256, 0, stream>>>(att, glogit, Hb1, x1, (float*)d_out, x0b, 0);
}

// Round 4
// 302.637 us; speedup vs baseline: 1.5687x; 1.0555x over previous
//
#include <hip/hip_runtime.h>
#include <cstdint>
#include <cstddef>

// B=16, N=512, D=768, H=8, F=96;  M = B*N = 8192; GEMM N-cols = 768(h) + 768(gate) = 1536; K = 768
typedef __attribute__((ext_vector_type(4))) float f32x4;
typedef __attribute__((ext_vector_type(8))) __bf16 bf16x8;
typedef __attribute__((ext_vector_type(8))) unsigned short u16x8;
typedef __attribute__((ext_vector_type(4))) unsigned short u16x4;

__device__ __forceinline__ unsigned short f2bf(float f){
  unsigned int u = __float_as_uint(f);
  u += 0x7fffu + ((u >> 16) & 1u);          // RNE
  return (unsigned short)(u >> 16);
}
__device__ __forceinline__ float bf2f(unsigned short u){
  return __uint_as_float(((unsigned int)u) << 16);
}
__device__ __forceinline__ float fast_tanh(float x){
  const float e = __expf(2.f * x);          // inf-safe: x>>0 -> 1-0; x<<0 -> 1-2
  return 1.f - 2.f / (e + 1.f);
}

__device__ __forceinline__ void gload_lds16(const void* g, void* l){
  __builtin_amdgcn_global_load_lds((const __attribute__((address_space(1))) void*)g,
                                   (__attribute__((address_space(3))) void*)l, 16, 0, 0);
}

__device__ __forceinline__ f32x4 mfma16(bf16x8 a, bf16x8 b, f32x4 c){
  return __builtin_amdgcn_mfma_f32_16x16x32_bf16(a, b, c, 0, 0, 0);
}

// ---------------- fp32 -> bf16 vector convert ----------------
__global__ __launch_bounds__(256) void f2b_kernel(const float* __restrict__ in,
                                                  unsigned short* __restrict__ out, int n4){
  int i = blockIdx.x * 256 + threadIdx.x;
  if (i >= n4) return;
  f32x4 v = ((const f32x4*)in)[i];
  union { unsigned short u[4]; unsigned long long ll; } o;
  #pragma unroll
  for (int e = 0; e < 4; ++e) o.u[e] = f2bf(v[e]);
  ((unsigned long long*)out)[i] = o.ll;
}

// ---------------- adjacency -> bitmask ----------------
__global__ __launch_bounds__(256) void mask_kernel(const float* __restrict__ adj,
                                                   unsigned int* __restrict__ mask){
  int idx = blockIdx.x * 256 + threadIdx.x;   // 16*512*16 = 131072 words
  const float* a = adj + (size_t)idx * 32;
  unsigned int m = 0;
  #pragma unroll
  for (int e = 0; e < 8; ++e){
    f32x4 v = *(const f32x4*)(a + e * 4);
    m |= (v[0] > 0.f ? 1u : 0u) << (e * 4);
    m |= (v[1] > 0.f ? 1u : 0u) << (e * 4 + 1);
    m |= (v[2] > 0.f ? 1u : 0u) << (e * 4 + 2);
    m |= (v[3] > 0.f ? 1u : 0u) << (e * 4 + 3);
  }
  mask[idx] = m;
}

// ---------------- build B^T (K-contiguous): rows 0..767 = Wcat col, 768..1535 = Hw row ----------------
__global__ __launch_bounds__(192) void buildBt_kernel(const float* __restrict__ W,   // [H][D][F]
                                                      const float* __restrict__ Hw,  // [D][D]
                                                      unsigned short* __restrict__ Bt){ // [1536][768]
  int n  = blockIdx.x;        // 0..1535
  int k4 = threadIdx.x;       // 0..191
  float v[4];
  if (n < 768){
    int head = n / 96, f = n % 96;
    const float* base = W + (size_t)head * 768 * 96 + f;
    #pragma unroll
    for (int e = 0; e < 4; ++e) v[e] = base[(size_t)(k4 * 4 + e) * 96];
  } else {
    f32x4 t = *(const f32x4*)(Hw + (size_t)(n - 768) * 768 + k4 * 4);
    #pragma unroll
    for (int e = 0; e < 4; ++e) v[e] = t[e];
  }
  union { unsigned short u[4]; unsigned long long ll; } o;
  #pragma unroll
  for (int e = 0; e < 4; ++e) o.u[e] = f2bf(v[e]);
  ((unsigned long long*)(Bt + (size_t)n * 768))[k4] = o.ll;
}

// ---------------- fused GEMM: C[8192][1536] = A[8192][768] * Bt^T  (BK=64) ----------------
// n<768  -> hb (bf16 [m][768]) + hT (bf16 [b*8+head][f][node]); n>=768 -> glogit bf16
__global__ __launch_bounds__(256, 2)
void gemm_kernel(const unsigned short* __restrict__ A,
                 const unsigned short* __restrict__ Bt,
                 unsigned short* __restrict__ hb,
                 unsigned short* __restrict__ hT,
                 unsigned short* __restrict__ glogit){
  __shared__ __align__(16) char lds[65536];   // 2 bufs * (A 16KB + B 16KB)
  const int tid  = threadIdx.x;
  const int wid  = tid >> 6;
  const int lane = tid & 63;
  // XCD-aware remap: XCD x gets mtiles [8x, 8x+8) x all 12 ntiles (A panel + Bt L2-resident)
  const int orig = blockIdx.x;
  const int wgid = (orig & 7) * 96 + (orig >> 3);
  const int mtile = wgid / 12, ntile = wgid % 12;
  const int m0 = mtile * 128, n0 = ntile * 128;
  const int wm = (wid >> 1) * 64, wn = (wid & 1) * 64;
  const int g = lane >> 4, r16 = lane & 15;

  // stage one BK=64 tile pair: 1024 chunks of 16B each for A and B.
  // linear LDS dest; XOR swizzle on SOURCE k-chunk: LDS[row][sp] holds k-chunk sp^(row&7)
  auto stage = [&](int kt, char* base){
    #pragma unroll
    for (int c = 0; c < 4; ++c){
      const int ch = c * 256 + tid;
      const int row = ch >> 3, sp = ch & 7;
      const int cj = sp ^ (row & 7);
      gload_lds16(A  + (size_t)(m0 + row) * 768 + kt * 64 + cj * 8, base + ch * 16);
      gload_lds16(Bt + (size_t)(n0 + row) * 768 + kt * 64 + cj * 8, base + 16384 + ch * 16);
    }
  };

  f32x4 acc[4][4];
  #pragma unroll
  for (int i = 0; i < 4; ++i)
    #pragma unroll
    for (int j = 0; j < 4; ++j) acc[i][j] = (f32x4){0.f, 0.f, 0.f, 0.f};

  stage(0, lds);
  __syncthreads();

  for (int kt = 0; kt < 12; ++kt){
    const int cur = kt & 1;
    if (kt < 11) stage(kt + 1, lds + (cur ^ 1) * 32768);
    const char* base = lds + cur * 32768;
    bf16x8 af[4][2], bfr[4][2];
    #pragma unroll
    for (int t = 0; t < 4; ++t){
      const int rowA = wm + t * 16 + r16;           // rowA&7 == r16&7
      const int rowB = wn + t * 16 + r16;
      #pragma unroll
      for (int kk = 0; kk < 2; ++kk){
        const int ckk = (kk << 2) | g;
        af[t][kk]  = *(const bf16x8*)(base + rowA * 128 + ((ckk ^ (rowA & 7)) << 4));
        bfr[t][kk] = *(const bf16x8*)(base + 16384 + rowB * 128 + ((ckk ^ (rowB & 7)) << 4));
      }
    }
    #pragma unroll
    for (int mt = 0; mt < 4; ++mt)
      #pragma unroll
      for (int nt = 0; nt < 4; ++nt){
        acc[mt][nt] = mfma16(af[mt][0], bfr[nt][0], acc[mt][nt]);
        acc[mt][nt] = mfma16(af[mt][1], bfr[nt][1], acc[mt][nt]);
      }
    __syncthreads();
  }

  if (n0 < 768){
    #pragma unroll
    for (int mt = 0; mt < 4; ++mt){
      #pragma unroll
      for (int nt = 0; nt < 4; ++nt){
        const int n = n0 + wn + nt * 16 + r16;
        const int head = n / 96, f = n % 96;
        #pragma unroll
        for (int r = 0; r < 4; ++r){
          const int m = m0 + wm + mt * 16 + g * 4 + r;
          const unsigned short v = f2bf(acc[mt][nt][r]);
          hb[(size_t)m * 768 + n] = v;
          const int b = m >> 9, node = m & 511;
          hT[(((size_t)(b * 8 + head)) * 96 + f) * 512 + node] = v;
        }
      }
    }
  } else {
    #pragma unroll
    for (int mt = 0; mt < 4; ++mt){
      #pragma unroll
      for (int nt = 0; nt < 4; ++nt){
        const int n = n0 + wn + nt * 16 + r16;
        #pragma unroll
        for (int r = 0; r < 4; ++r){
          const int m = m0 + wm + mt * 16 + g * 4 + r;
          glogit[(size_t)m * 768 + (n - 768)] = f2bf(acc[mt][nt][r]);
        }
      }
    }
  }
}

// ---------------- s/d projections from bf16 h ----------------
__global__ __launch_bounds__(256)
void sd_kernel(const unsigned short* __restrict__ h, const float* __restrict__ asrc,
               const float* __restrict__ adst, float* __restrict__ s, float* __restrict__ d){
  const int idx  = blockIdx.x * 4 + (threadIdx.x >> 6);   // (m,head): idx = m*8+head
  const int lane = threadIdx.x & 63;
  const int m = idx >> 3, head = idx & 7;
  const unsigned short* hr = h + (size_t)m * 768 + head * 96;
  const float* as_ = asrc + head * 96;
  const float* ad_ = adst + head * 96;
  float t1 = fast_tanh(bf2f(hr[lane]));
  float ss = t1 * as_[lane];
  float dd = t1 * ad_[lane];
  if (lane < 32){
    float t2 = fast_tanh(bf2f(hr[64 + lane]));
    ss += t2 * as_[64 + lane];
    dd += t2 * ad_[64 + lane];
  }
  #pragma unroll
  for (int o = 32; o > 0; o >>= 1){ ss += __shfl_xor(ss, o); dd += __shfl_xor(dd, o); }
  if (lane == 0){
    const int b = m >> 9, node = m & 511;
    const int o = ((b * 8 + head) << 9) + node;
    s[o] = ss; d[o] = dd;
  }
}

// ---------------- fused attention + softmax-PV + gate/ELU/residual/scramble ----------------
__global__ __launch_bounds__(256)
void attn_kernel(const float* __restrict__ s, const float* __restrict__ d,
                 const unsigned int* __restrict__ mask,   // [B][512][16]
                 const unsigned short* __restrict__ hT,   // [BH][F][N] bf16
                 const float* __restrict__ bias,          // [F]
                 const unsigned short* __restrict__ glogit, // [8192][768] bf16
                 const float* __restrict__ Hb,            // [768]
                 const float* __restrict__ xin,           // [8192][768] fp32 residual
                 float* __restrict__ outf,                // [8192][768] fp32
                 unsigned short* __restrict__ outb,       // bf16 copy (next-layer A)
                 int write_b){
  const int idx = blockIdx.x;           // bh = idx&127 keeps same-bh blocks on one XCD
  const int bh = idx & 127, ib = idx >> 7;
  const int b  = bh >> 3;
  const int tid = threadIdx.x, wid = tid >> 6, lane = tid & 63;
  const int g = lane >> 4, r16 = lane & 15;
  const int rowbase = ib * 64 + wid * 16;

  __shared__ float d_lds[512];
  __shared__ float hb_lds[768];
  __shared__ float bias_lds[96];
  __shared__ __align__(16) char vbuf[2][12288];   // [96 f][8 slots][16B], slot content = slot^(row&7)
  const float* dv = d + bh * 512;
  if (tid < 128) ((f32x4*)d_lds)[tid] = ((const f32x4*)dv)[tid];
  if (tid >= 128 && tid < 128 + 24) ((f32x4*)bias_lds)[tid - 128] = ((const f32x4*)bias)[tid - 128];
  if (tid < 192) ((f32x4*)hb_lds)[tid] = ((const f32x4*)Hb)[tid];

  const unsigned short* hTb = hT + (size_t)bh * 96 * 512;

  auto stage = [&](int p, int bufi){
    #pragma unroll
    for (int ss2 = 0; ss2 < 3; ++ss2){
      const int ch = ss2 * 256 + tid;
      const int row = ch >> 3, slotpos = ch & 7;
      const int cj = slotpos ^ (row & 7);
      gload_lds16(hTb + (size_t)row * 512 + p * 64 + cj * 8, vbuf[bufi] + ch * 16);
    }
  };

  const int i_mine = rowbase + r16;     // this lane's P-row
  const float s_i = s[bh * 512 + i_mine];

  unsigned int mw[16];
  {
    const uint4* mrow = (const uint4*)(mask + ((size_t)b * 512 + i_mine) * 16);
    uint4 a0 = mrow[0], a1 = mrow[1], a2 = mrow[2], a3 = mrow[3];
    mw[0]=a0.x; mw[1]=a0.y; mw[2]=a0.z; mw[3]=a0.w;
    mw[4]=a1.x; mw[5]=a1.y; mw[6]=a1.z; mw[7]=a1.w;
    mw[8]=a2.x; mw[9]=a2.y; mw[10]=a2.z; mw[11]=a2.w;
    mw[12]=a3.x; mw[13]=a3.y; mw[14]=a3.z; mw[15]=a3.w;
  }

  stage(0, 0);
  __syncthreads();   // drains stage(0) + d_lds/bias/Hb

  // per-bh UNMASKED max of d: valid upper bound since lrelu is monotone
  float Mx = d_lds[lane];
  #pragma unroll
  for (int t = 1; t < 8; ++t) Mx = fmaxf(Mx, d_lds[t * 64 + lane]);
  #pragma unroll
  for (int o = 32; o > 0; o >>= 1) Mx = fmaxf(Mx, __shfl_xor(Mx, o));
  const float scm = s_i + Mx;
  const float m_i = fmaxf(scm, 0.2f * scm);

  f32x4 acc2[6];
  #pragma unroll
  for (int ft = 0; ft < 6; ++ft) acc2[ft] = (f32x4){0.f, 0.f, 0.f, 0.f};
  float L = 0.f;

  for (int p = 0; p < 8; ++p){
    if (p < 7) stage(p + 1, (p + 1) & 1);
    const char* vb = vbuf[p & 1];
    #pragma unroll
    for (int half = 0; half < 2; ++half){
      const int jt = p * 2 + half;
      const unsigned int w = mw[jt];
      const int j8 = jt * 32 + g * 8;
      f32x4 dA = *(const f32x4*)(d_lds + j8);
      f32x4 dB = *(const f32x4*)(d_lds + j8 + 4);
      u16x8 pa;
      #pragma unroll
      for (int e = 0; e < 4; ++e){
        float sc = s_i + dA[e]; sc = fmaxf(sc, 0.2f * sc);
        float p1 = ((w >> (g * 8 + e)) & 1u) ? __expf(sc - m_i) : 0.f;
        L += p1; pa[e] = f2bf(p1);
        float sc2 = s_i + dB[e]; sc2 = fmaxf(sc2, 0.2f * sc2);
        float p2 = ((w >> (g * 8 + 4 + e)) & 1u) ? __expf(sc2 - m_i) : 0.f;
        L += p2; pa[4 + e] = f2bf(p2);
      }
      const bf16x8 af = __builtin_bit_cast(bf16x8, pa);
      const int slot = ((half * 4 + g) ^ (r16 & 7)) * 16;
      #pragma unroll
      for (int ft = 0; ft < 6; ++ft){
        bf16x8 vf = *(const bf16x8*)(vb + (ft * 16 + r16) * 128 + slot);
        acc2[ft] = mfma16(af, vf, acc2[ft]);
      }
    }
    __syncthreads();
  }

  L += __shfl_xor(L, 16);
  L += __shfl_xor(L, 32);
  const float linv = 1.f / L;
  float lr[4];
  #pragma unroll
  for (int r = 0; r < 4; ++r) lr[r] = __shfl(linv, g * 4 + r);  // linv of row rowbase+g*4+r

  // fused combine epilogue: attn tile (bh, ib) covers out rows
  // m_out = (2h + b>>3)*512 + (b&7)*64 + ib*8 + (node>>3)&7 ; cc = (node&7)*96 + f
  const int hh = bh & 7;
  const int bb2 = (hh << 1) | (b >> 3);
  const int mbase = bb2 * 512 + ((b & 7) << 6) + ib * 8;
  #pragma unroll
  for (int ft = 0; ft < 6; ++ft){
    const int f = ft * 16 + r16;
    const float bv = bias_lds[f];
    #pragma unroll
    for (int r = 0; r < 4; ++r){
      const int node = rowbase + g * 4 + r;
      const float attv = acc2[ft][r] * lr[r] + bv;
      const int cc = (node & 7) * 96 + f;
      const size_t oidx = (size_t)(mbase + ((node >> 3) & 7)) * 768 + cc;
      const float gate = 1.f / (1.f + __expf(-(bf2f(glogit[oidx]) + hb_lds[cc])));
      const float eluv = attv > 0.f ? attv : (__expf(attv) - 1.f);
      const float o = gate * eluv + (1.f - gate) * xin[oidx];
      outf[oidx] = o;
      if (write_b) outb[oidx] = f2bf(o);
    }
  }
}

extern "C" void kernel_launch(void* const* d_in, const int* in_sizes, int n_in,
                              void* d_out, int out_size, void* d_ws, size_t ws_size,
                              hipStream_t stream){
  const float* emb   = (const float*)d_in[0];
  const float* adj   = (const float*)d_in[1];
  const float* W0    = (const float*)d_in[3];
  const float* b0    = (const float*)d_in[4];
  const float* asrc0 = (const float*)d_in[5];
  const float* adst0 = (const float*)d_in[6];
  const float* Hw0   = (const float*)d_in[7];
  const float* Hb0   = (const float*)d_in[8];
  const float* W1    = (const float*)d_in[9];
  const float* b1    = (const float*)d_in[10];
  const float* asrc1 = (const float*)d_in[11];
  const float* adst1 = (const float*)d_in[12];
  const float* Hw1   = (const float*)d_in[13];
  const float* Hb1   = (const float*)d_in[14];

  char* ws = (char*)d_ws;
  size_t off = 0;
  auto alloc = [&](size_t bytes){ void* p = ws + off; off += (bytes + 255) & ~(size_t)255; return p; };
  unsigned short* x0b  = (unsigned short*)alloc(8192ull * 768 * 2);  // layer A input (bf16), rewritten by attn L1
  unsigned short* Bt0  = (unsigned short*)alloc(1536ull * 768 * 2);
  unsigned short* Bt1  = (unsigned short*)alloc(1536ull * 768 * 2);
  unsigned short* hb   = (unsigned short*)alloc(8192ull * 768 * 2);
  unsigned short* hT   = (unsigned short*)alloc(8192ull * 768 * 2);
  unsigned short* glogit = (unsigned short*)alloc(8192ull * 768 * 2);
  float* sbuf          = (float*)alloc(65536ull * 4);
  float* dbuf          = (float*)alloc(65536ull * 4);
  float* x1            = (float*)alloc(8192ull * 768 * 4);
  unsigned int* mask   = (unsigned int*)alloc(16ull * 512 * 16 * 4);
  (void)ws_size; (void)in_sizes; (void)n_in; (void)out_size;

  f2b_kernel<<<6144, 256, 0, stream>>>(emb, x0b, 1572864);
  mask_kernel<<<512, 256, 0, stream>>>(adj, mask);
  buildBt_kernel<<<1536, 192, 0, stream>>>(W0, Hw0, Bt0);
  buildBt_kernel<<<1536, 192, 0, stream>>>(W1, Hw1, Bt1);

  // layer 1
  gemm_kernel<<<768, 256, 0, stream>>>(x0b, Bt0, hb, hT, glogit);
  sd_kernel<<<16384, 256, 0, stream>>>(hb, asrc0, adst0, sbuf, dbuf);
  attn_kernel<<<1024, 256, 0, stream>>>(sbuf, dbuf, mask, hT, b0, glogit, Hb0, emb, x1, x0b, 1);

  // layer 2 (x0b now holds bf16 of x1)
  gemm_kernel<<<768, 256, 0, stream>>>(x0b, Bt1, hb, hT, glogit);
  sd_kernel<<<16384, 256, 0, stream>>>(hb, asrc1, adst1, sbuf, dbuf);
  attn_kernel<<<1024, 256, 0, stream>>>(sbuf, dbuf, mask, hT, b1, glogit, Hb1, x1, (float*)d_out, x0b, 0);
}

// Round 5
// 288.424 us; speedup vs baseline: 1.6460x; 1.0493x over previous
//
#include <hip/hip_runtime.h>
#include <cstdint>
#include <cstddef>

// B=16, N=512, D=768, H=8, F=96;  M = B*N = 8192; GEMM N-cols = 768(h) + 768(gate) = 1536; K = 768
typedef __attribute__((ext_vector_type(4))) float f32x4;
typedef __attribute__((ext_vector_type(8))) __bf16 bf16x8;
typedef __attribute__((ext_vector_type(8))) unsigned short u16x8;
typedef __attribute__((ext_vector_type(4))) unsigned short u16x4;

__device__ __forceinline__ unsigned short f2bf(float f){
  unsigned int u = __float_as_uint(f);
  u += 0x7fffu + ((u >> 16) & 1u);          // RNE
  return (unsigned short)(u >> 16);
}
__device__ __forceinline__ float bf2f(unsigned short u){
  return __uint_as_float(((unsigned int)u) << 16);
}
__device__ __forceinline__ float fast_tanh(float x){
  const float e = __expf(2.f * x);          // inf-safe: x>>0 -> 1-0; x<<0 -> 1-2
  return 1.f - 2.f / (e + 1.f);
}

__device__ __forceinline__ void gload_lds16(const void* g, void* l){
  __builtin_amdgcn_global_load_lds((const __attribute__((address_space(1))) void*)g,
                                   (__attribute__((address_space(3))) void*)l, 16, 0, 0);
}

__device__ __forceinline__ f32x4 mfma16(bf16x8 a, bf16x8 b, f32x4 c){
  return __builtin_amdgcn_mfma_f32_16x16x32_bf16(a, b, c, 0, 0, 0);
}

// ---------------- merged prep: fp32->bf16 convert (blocks 0..6143) + adj bitmask (6144..6655) ----------------
__global__ __launch_bounds__(256) void prep_kernel(const float* __restrict__ in,
                                                   unsigned short* __restrict__ out,
                                                   const float* __restrict__ adj,
                                                   unsigned int* __restrict__ mask){
  const int bid = blockIdx.x;
  if (bid < 6144){
    int i = bid * 256 + threadIdx.x;
    f32x4 v = ((const f32x4*)in)[i];
    union { unsigned short u[4]; unsigned long long ll; } o;
    #pragma unroll
    for (int e = 0; e < 4; ++e) o.u[e] = f2bf(v[e]);
    ((unsigned long long*)out)[i] = o.ll;
  } else {
    int idx = (bid - 6144) * 256 + threadIdx.x;   // 131072 words
    const float* a = adj + (size_t)idx * 32;
    unsigned int m = 0;
    #pragma unroll
    for (int e = 0; e < 8; ++e){
      f32x4 v = *(const f32x4*)(a + e * 4);
      m |= (v[0] > 0.f ? 1u : 0u) << (e * 4);
      m |= (v[1] > 0.f ? 1u : 0u) << (e * 4 + 1);
      m |= (v[2] > 0.f ? 1u : 0u) << (e * 4 + 2);
      m |= (v[3] > 0.f ? 1u : 0u) << (e * 4 + 3);
    }
    mask[idx] = m;
  }
}

// ---------------- build B^T for both layers: rows 0..767 = Wcat col, 768..1535 = Hw row ----------------
__global__ __launch_bounds__(192) void buildBt_kernel(const float* __restrict__ W0,
                                                      const float* __restrict__ Hw0,
                                                      unsigned short* __restrict__ Bt0,
                                                      const float* __restrict__ W1,
                                                      const float* __restrict__ Hw1,
                                                      unsigned short* __restrict__ Bt1){
  const int bid = blockIdx.x;                 // 0..3071
  const int layer = bid >= 1536;
  const int n = layer ? bid - 1536 : bid;     // 0..1535
  const float* W  = layer ? W1  : W0;
  const float* Hw = layer ? Hw1 : Hw0;
  unsigned short* Bt = layer ? Bt1 : Bt0;
  int k4 = threadIdx.x;       // 0..191
  float v[4];
  if (n < 768){
    int head = n / 96, f = n % 96;
    const float* base = W + (size_t)head * 768 * 96 + f;
    #pragma unroll
    for (int e = 0; e < 4; ++e) v[e] = base[(size_t)(k4 * 4 + e) * 96];
  } else {
    f32x4 t = *(const f32x4*)(Hw + (size_t)(n - 768) * 768 + k4 * 4);
    #pragma unroll
    for (int e = 0; e < 4; ++e) v[e] = t[e];
  }
  union { unsigned short u[4]; unsigned long long ll; } o;
  #pragma unroll
  for (int e = 0; e < 4; ++e) o.u[e] = f2bf(v[e]);
  ((unsigned long long*)(Bt + (size_t)n * 768))[k4] = o.ll;
}

// ---------------- fused GEMM: C[8192][1536] = A[8192][768] * Bt^T  (BM=128, BN=64, BK=64) ----------------
// ntile<12 -> hb (bf16 [m][768]) + hT (bf16 [b*8+head][f][node]); else -> glogit bf16 (with Hb pre-added)
__global__ __launch_bounds__(256, 3)
void gemm_kernel(const unsigned short* __restrict__ A,
                 const unsigned short* __restrict__ Bt,
                 const float* __restrict__ Hb,
                 unsigned short* __restrict__ hb,
                 unsigned short* __restrict__ hT,
                 unsigned short* __restrict__ glogit){
  __shared__ __align__(16) char lds[49152];   // 2 bufs * (A 16KB + B 8KB)
  const int tid  = threadIdx.x;
  const int wid  = tid >> 6;
  const int lane = tid & 63;
  // XCD-aware remap: XCD x gets mtiles [8x,8x+8) x all 24 ntiles (A panel + Bt L2-resident)
  const int orig = blockIdx.x;                 // 0..1535
  const int wgid = (orig & 7) * 192 + (orig >> 3);
  const int mtile = wgid / 24, ntile = wgid % 24;
  const int m0 = mtile * 128, n0 = ntile * 64;
  const int wm = (wid >> 1) * 64, wn = (wid & 1) * 32;
  const int g = lane >> 4, r16 = lane & 15;

  // stage BK=64 tiles: A 1024 chunks (4/thr), B 512 chunks (2/thr), 16B each.
  // linear LDS dest; XOR swizzle on SOURCE: LDS[row][sp] holds k-chunk sp^(row&7)
  auto stage = [&](int kt, char* base){
    #pragma unroll
    for (int c = 0; c < 4; ++c){
      const int ch = c * 256 + tid;
      const int row = ch >> 3, sp = ch & 7;
      const int cj = sp ^ (row & 7);
      gload_lds16(A + (size_t)(m0 + row) * 768 + kt * 64 + cj * 8, base + ch * 16);
    }
    #pragma unroll
    for (int c = 0; c < 2; ++c){
      const int ch = c * 256 + tid;
      const int row = ch >> 3, sp = ch & 7;
      const int cj = sp ^ (row & 7);
      gload_lds16(Bt + (size_t)(n0 + row) * 768 + kt * 64 + cj * 8, base + 16384 + ch * 16);
    }
  };

  f32x4 acc[4][2];
  #pragma unroll
  for (int i = 0; i < 4; ++i)
    #pragma unroll
    for (int j = 0; j < 2; ++j) acc[i][j] = (f32x4){0.f, 0.f, 0.f, 0.f};

  stage(0, lds);
  __syncthreads();

  for (int kt = 0; kt < 12; ++kt){
    const int cur = kt & 1;
    if (kt < 11) stage(kt + 1, lds + (cur ^ 1) * 24576);
    const char* base = lds + cur * 24576;
    bf16x8 af[4][2], bfr[2][2];
    #pragma unroll
    for (int t = 0; t < 4; ++t){
      const int rowA = wm + t * 16 + r16;
      #pragma unroll
      for (int kk = 0; kk < 2; ++kk){
        const int ckk = (kk << 2) | g;
        af[t][kk] = *(const bf16x8*)(base + rowA * 128 + ((ckk ^ (rowA & 7)) << 4));
      }
    }
    #pragma unroll
    for (int nt = 0; nt < 2; ++nt){
      const int rowB = wn + nt * 16 + r16;
      #pragma unroll
      for (int kk = 0; kk < 2; ++kk){
        const int ckk = (kk << 2) | g;
        bfr[nt][kk] = *(const bf16x8*)(base + 16384 + rowB * 128 + ((ckk ^ (rowB & 7)) << 4));
      }
    }
    #pragma unroll
    for (int mt = 0; mt < 4; ++mt)
      #pragma unroll
      for (int nt = 0; nt < 2; ++nt){
        acc[mt][nt] = mfma16(af[mt][0], bfr[nt][0], acc[mt][nt]);
        acc[mt][nt] = mfma16(af[mt][1], bfr[nt][1], acc[mt][nt]);
      }
    __syncthreads();
  }

  if (n0 < 768){
    #pragma unroll
    for (int mt = 0; mt < 4; ++mt){
      #pragma unroll
      for (int nt = 0; nt < 2; ++nt){
        const int n = n0 + wn + nt * 16 + r16;
        const int head = n / 96, f = n % 96;
        #pragma unroll
        for (int r = 0; r < 4; ++r){
          const int m = m0 + wm + mt * 16 + g * 4 + r;
          const unsigned short v = f2bf(acc[mt][nt][r]);
          hb[(size_t)m * 768 + n] = v;
          const int b = m >> 9, node = m & 511;
          hT[(((size_t)(b * 8 + head)) * 96 + f) * 512 + node] = v;
        }
      }
    }
  } else {
    #pragma unroll
    for (int mt = 0; mt < 4; ++mt){
      #pragma unroll
      for (int nt = 0; nt < 2; ++nt){
        const int n = n0 + wn + nt * 16 + r16;
        const float hbv = Hb[n - 768];           // pre-add gate bias (fp32, before bf16 round)
        #pragma unroll
        for (int r = 0; r < 4; ++r){
          const int m = m0 + wm + mt * 16 + g * 4 + r;
          glogit[(size_t)m * 768 + (n - 768)] = f2bf(acc[mt][nt][r] + hbv);
        }
      }
    }
  }
}

// ---------------- s/d projections from bf16 h ----------------
__global__ __launch_bounds__(256)
void sd_kernel(const unsigned short* __restrict__ h, const float* __restrict__ asrc,
               const float* __restrict__ adst, float* __restrict__ s, float* __restrict__ d){
  const int idx  = blockIdx.x * 4 + (threadIdx.x >> 6);   // (m,head): idx = m*8+head
  const int lane = threadIdx.x & 63;
  const int m = idx >> 3, head = idx & 7;
  const unsigned short* hr = h + (size_t)m * 768 + head * 96;
  const float* as_ = asrc + head * 96;
  const float* ad_ = adst + head * 96;
  float t1 = fast_tanh(bf2f(hr[lane]));
  float ss = t1 * as_[lane];
  float dd = t1 * ad_[lane];
  if (lane < 32){
    float t2 = fast_tanh(bf2f(hr[64 + lane]));
    ss += t2 * as_[64 + lane];
    dd += t2 * ad_[64 + lane];
  }
  #pragma unroll
  for (int o = 32; o > 0; o >>= 1){ ss += __shfl_xor(ss, o); dd += __shfl_xor(dd, o); }
  if (lane == 0){
    const int b = m >> 9, node = m & 511;
    const int o = ((b * 8 + head) << 9) + node;
    s[o] = ss; d[o] = dd;
  }
}

// ---------------- fused attention + softmax-PV + gate/ELU/residual/scramble ----------------
__global__ __launch_bounds__(256)
void attn_kernel(const float* __restrict__ s, const float* __restrict__ d,
                 const unsigned int* __restrict__ mask,     // [B][512][16]
                 const unsigned short* __restrict__ hT,     // [BH][F][N] bf16
                 const float* __restrict__ bias,            // [F]
                 const unsigned short* __restrict__ glogit, // [8192][768] bf16 (Hb pre-added)
                 const float* __restrict__ xin,             // [8192][768] fp32 residual
                 float* __restrict__ outf,                  // [8192][768] fp32
                 unsigned short* __restrict__ outb,         // bf16 copy (next-layer A)
                 int write_b){
  const int idx = blockIdx.x;           // bh = idx&127 keeps same-bh blocks on one XCD
  const int bh = idx & 127, ib = idx >> 7;
  const int b  = bh >> 3;
  const int tid = threadIdx.x, wid = tid >> 6, lane = tid & 63;
  const int g = lane >> 4, r16 = lane & 15;
  const int rowbase = ib * 64 + wid * 16;

  __shared__ float d_lds[512];
  __shared__ float bias_lds[96];
  __shared__ __align__(16) char vbuf[2][12288];   // V slices; reused as fp32 out tile [8][768]
  float* att_s = (float*)vbuf;

  const float* dv = d + bh * 512;
  if (tid < 128) ((f32x4*)d_lds)[tid] = ((const f32x4*)dv)[tid];
  if (tid >= 128 && tid < 152) ((f32x4*)bias_lds)[tid - 128] = ((const f32x4*)bias)[tid - 128];

  const unsigned short* hTb = hT + (size_t)bh * 96 * 512;

  auto stage = [&](int p, int bufi){
    #pragma unroll
    for (int ss2 = 0; ss2 < 3; ++ss2){
      const int ch = ss2 * 256 + tid;
      const int row = ch >> 3, slotpos = ch & 7;
      const int cj = slotpos ^ (row & 7);
      gload_lds16(hTb + (size_t)row * 512 + p * 64 + cj * 8, vbuf[bufi] + ch * 16);
    }
  };

  const int i_mine = rowbase + r16;     // this lane's P-row
  const float s_i = s[bh * 512 + i_mine];

  unsigned int mw[16];
  {
    const uint4* mrow = (const uint4*)(mask + ((size_t)b * 512 + i_mine) * 16);
    uint4 a0 = mrow[0], a1 = mrow[1], a2 = mrow[2], a3 = mrow[3];
    mw[0]=a0.x; mw[1]=a0.y; mw[2]=a0.z; mw[3]=a0.w;
    mw[4]=a1.x; mw[5]=a1.y; mw[6]=a1.z; mw[7]=a1.w;
    mw[8]=a2.x; mw[9]=a2.y; mw[10]=a2.z; mw[11]=a2.w;
    mw[12]=a3.x; mw[13]=a3.y; mw[14]=a3.z; mw[15]=a3.w;
  }

  stage(0, 0);
  __syncthreads();   // drains stage(0) + d_lds/bias

  // per-bh UNMASKED max of d: valid upper bound since lrelu is monotone
  float Mx = d_lds[lane];
  #pragma unroll
  for (int t = 1; t < 8; ++t) Mx = fmaxf(Mx, d_lds[t * 64 + lane]);
  #pragma unroll
  for (int o = 32; o > 0; o >>= 1) Mx = fmaxf(Mx, __shfl_xor(Mx, o));
  const float scm = s_i + Mx;
  const float m_i = fmaxf(scm, 0.2f * scm);

  f32x4 acc2[6];
  #pragma unroll
  for (int ft = 0; ft < 6; ++ft) acc2[ft] = (f32x4){0.f, 0.f, 0.f, 0.f};
  float L = 0.f;

  for (int p = 0; p < 8; ++p){
    if (p < 7) stage(p + 1, (p + 1) & 1);
    const char* vb = vbuf[p & 1];
    #pragma unroll
    for (int half = 0; half < 2; ++half){
      const int jt = p * 2 + half;
      const unsigned int w = mw[jt];
      const int j8 = jt * 32 + g * 8;
      f32x4 dA = *(const f32x4*)(d_lds + j8);
      f32x4 dB = *(const f32x4*)(d_lds + j8 + 4);
      u16x8 pa;
      #pragma unroll
      for (int e = 0; e < 4; ++e){
        float sc = s_i + dA[e]; sc = fmaxf(sc, 0.2f * sc);
        float p1 = ((w >> (g * 8 + e)) & 1u) ? __expf(sc - m_i) : 0.f;
        L += p1; pa[e] = f2bf(p1);
        float sc2 = s_i + dB[e]; sc2 = fmaxf(sc2, 0.2f * sc2);
        float p2 = ((w >> (g * 8 + 4 + e)) & 1u) ? __expf(sc2 - m_i) : 0.f;
        L += p2; pa[4 + e] = f2bf(p2);
      }
      const bf16x8 af = __builtin_bit_cast(bf16x8, pa);
      const int slot = ((half * 4 + g) ^ (r16 & 7)) * 16;
      #pragma unroll
      for (int ft = 0; ft < 6; ++ft){
        bf16x8 vf = *(const bf16x8*)(vb + (ft * 16 + r16) * 128 + slot);
        acc2[ft] = mfma16(af, vf, acc2[ft]);
      }
    }
    __syncthreads();
  }

  L += __shfl_xor(L, 16);
  L += __shfl_xor(L, 32);
  const float linv = 1.f / L;
  float lr[4];
  #pragma unroll
  for (int r = 0; r < 4; ++r) lr[r] = __shfl(linv, g * 4 + r);  // linv of row rowbase+g*4+r

  // phase 1: scatter normalized attn (+bias) into LDS out-tile [8][768]
  // out rows m = mbase + (node>>3)&7 ; col cc = (node&7)*96 + f
  #pragma unroll
  for (int ft = 0; ft < 6; ++ft){
    const int f = ft * 16 + r16;
    const float bv = bias_lds[f];
    #pragma unroll
    for (int r = 0; r < 4; ++r){
      const int node = rowbase + g * 4 + r;
      att_s[((node >> 3) & 7) * 768 + (node & 7) * 96 + f] = acc2[ft][r] * lr[r] + bv;
    }
  }
  __syncthreads();

  // phase 2: coalesced fused gate/ELU/residual over the contiguous 8-row global range
  const int hh = bh & 7;
  const int bb2 = (hh << 1) | (b >> 3);
  const int mbase = bb2 * 512 + ((b & 7) << 6) + ib * 8;
  const size_t gb4 = (size_t)mbase * 192;     // f32x4 index: mbase*768/4
  #pragma unroll
  for (int sgi = 0; sgi < 6; ++sgi){
    const int ei = sgi * 256 + tid;
    f32x4 a4 = ((const f32x4*)att_s)[ei];
    u16x4 gl = ((const u16x4*)glogit)[gb4 + ei];
    f32x4 xv = ((const f32x4*)xin)[gb4 + ei];
    f32x4 o;
    #pragma unroll
    for (int e = 0; e < 4; ++e){
      const float gate = 1.f / (1.f + __expf(-bf2f(gl[e])));
      const float a = a4[e];
      const float eluv = a > 0.f ? a : (__expf(a) - 1.f);
      o[e] = gate * eluv + (1.f - gate) * xv[e];
    }
    ((f32x4*)outf)[gb4 + ei] = o;
    if (write_b){
      union { unsigned short u[4]; unsigned long long ll; } ob;
      #pragma unroll
      for (int e = 0; e < 4; ++e) ob.u[e] = f2bf(o[e]);
      ((unsigned long long*)outb)[gb4 + ei] = ob.ll;
    }
  }
}

extern "C" void kernel_launch(void* const* d_in, const int* in_sizes, int n_in,
                              void* d_out, int out_size, void* d_ws, size_t ws_size,
                              hipStream_t stream){
  const float* emb   = (const float*)d_in[0];
  const float* adj   = (const float*)d_in[1];
  const float* W0    = (const float*)d_in[3];
  const float* b0    = (const float*)d_in[4];
  const float* asrc0 = (const float*)d_in[5];
  const float* adst0 = (const float*)d_in[6];
  const float* Hw0   = (const float*)d_in[7];
  const float* Hb0   = (const float*)d_in[8];
  const float* W1    = (const float*)d_in[9];
  const float* b1    = (const float*)d_in[10];
  const float* asrc1 = (const float*)d_in[11];
  const float* adst1 = (const float*)d_in[12];
  const float* Hw1   = (const float*)d_in[13];
  const float* Hb1   = (const float*)d_in[14];

  char* ws = (char*)d_ws;
  size_t off = 0;
  auto alloc = [&](size_t bytes){ void* p = ws + off; off += (bytes + 255) & ~(size_t)255; return p; };
  unsigned short* x0b  = (unsigned short*)alloc(8192ull * 768 * 2);  // layer A input (bf16), rewritten by attn L1
  unsigned short* Bt0  = (unsigned short*)alloc(1536ull * 768 * 2);
  unsigned short* Bt1  = (unsigned short*)alloc(1536ull * 768 * 2);
  unsigned short* hb   = (unsigned short*)alloc(8192ull * 768 * 2);
  unsigned short* hT   = (unsigned short*)alloc(8192ull * 768 * 2);
  unsigned short* glogit = (unsigned short*)alloc(8192ull * 768 * 2);
  float* sbuf          = (float*)alloc(65536ull * 4);
  float* dbuf          = (float*)alloc(65536ull * 4);
  float* x1            = (float*)alloc(8192ull * 768 * 4);
  unsigned int* mask   = (unsigned int*)alloc(16ull * 512 * 16 * 4);
  (void)ws_size; (void)in_sizes; (void)n_in; (void)out_size;

  prep_kernel<<<6656, 256, 0, stream>>>(emb, x0b, adj, mask);
  buildBt_kernel<<<3072, 192, 0, stream>>>(W0, Hw0, Bt0, W1, Hw1, Bt1);

  // layer 1
  gemm_kernel<<<1536, 256, 0, stream>>>(x0b, Bt0, Hb0, hb, hT, glogit);
  sd_kernel<<<16384, 256, 0, stream>>>(hb, asrc0, adst0, sbuf, dbuf);
  attn_kernel<<<1024, 256, 0, stream>>>(sbuf, dbuf, mask, hT, b0, glogit, emb, x1, x0b, 1);

  // layer 2 (x0b now holds bf16 of x1)
  gemm_kernel<<<1536, 256, 0, stream>>>(x0b, Bt1, Hb1, hb, hT, glogit);
  sd_kernel<<<16384, 256, 0, stream>>>(hb, asrc1, adst1, sbuf, dbuf);
  attn_kernel<<<1024, 256, 0, stream>>>(sbuf, dbuf, mask, hT, b1, glogit, x1, (float*)d_out, x0b, 0);
}

// Round 6
// 248.242 us; speedup vs baseline: 1.9125x; 1.1619x over previous
//
#include <hip/hip_runtime.h>
#include <cstdint>
#include <cstddef>

// B=16, N=512, D=768, H=8, F=96;  M = B*N = 8192; GEMM N-cols = 768(h) + 768(gate) = 1536; K = 768
typedef __attribute__((ext_vector_type(4))) float f32x4;
typedef __attribute__((ext_vector_type(8))) __bf16 bf16x8;
typedef __attribute__((ext_vector_type(8))) unsigned short u16x8;
typedef __attribute__((ext_vector_type(4))) unsigned short u16x4;

__device__ __forceinline__ unsigned short f2bf(float f){
  unsigned int u = __float_as_uint(f);
  u += 0x7fffu + ((u >> 16) & 1u);          // RNE
  return (unsigned short)(u >> 16);
}
__device__ __forceinline__ float bf2f(unsigned short u){
  return __uint_as_float(((unsigned int)u) << 16);
}
__device__ __forceinline__ float fast_tanh(float x){
  const float e = __expf(2.f * x);          // inf-safe: x>>0 -> 1-0; x<<0 -> 1-2
  return 1.f - 2.f / (e + 1.f);
}

__device__ __forceinline__ void gload_lds16(const void* g, void* l){
  __builtin_amdgcn_global_load_lds((const __attribute__((address_space(1))) void*)g,
                                   (__attribute__((address_space(3))) void*)l, 16, 0, 0);
}

__device__ __forceinline__ f32x4 mfma16(bf16x8 a, bf16x8 b, f32x4 c){
  return __builtin_amdgcn_mfma_f32_16x16x32_bf16(a, b, c, 0, 0, 0);
}

// ---------------- merged prep: emb fp32->bf16 (0..6143) + adj bitmask (6144..6655) + Bt both layers (6656..9727) ----------------
__global__ __launch_bounds__(256) void prep_kernel(const float* __restrict__ in,
                                                   unsigned short* __restrict__ out,
                                                   const float* __restrict__ adj,
                                                   unsigned int* __restrict__ mask,
                                                   const float* __restrict__ W0,
                                                   const float* __restrict__ Hw0,
                                                   unsigned short* __restrict__ Bt0,
                                                   const float* __restrict__ W1,
                                                   const float* __restrict__ Hw1,
                                                   unsigned short* __restrict__ Bt1){
  const int bid = blockIdx.x;
  if (bid < 6144){
    int i = bid * 256 + threadIdx.x;
    f32x4 v = ((const f32x4*)in)[i];
    union { unsigned short u[4]; unsigned long long ll; } o;
    #pragma unroll
    for (int e = 0; e < 4; ++e) o.u[e] = f2bf(v[e]);
    ((unsigned long long*)out)[i] = o.ll;
  } else if (bid < 6656){
    int idx = (bid - 6144) * 256 + threadIdx.x;   // 131072 words
    const float* a = adj + (size_t)idx * 32;
    unsigned int m = 0;
    #pragma unroll
    for (int e = 0; e < 8; ++e){
      f32x4 v = *(const f32x4*)(a + e * 4);
      m |= (v[0] > 0.f ? 1u : 0u) << (e * 4);
      m |= (v[1] > 0.f ? 1u : 0u) << (e * 4 + 1);
      m |= (v[2] > 0.f ? 1u : 0u) << (e * 4 + 2);
      m |= (v[3] > 0.f ? 1u : 0u) << (e * 4 + 3);
    }
    mask[idx] = m;
  } else {
    const int rel = bid - 6656;                  // 0..3071
    const int layer = rel >= 1536;
    const int n = layer ? rel - 1536 : rel;      // 0..1535
    const float* W  = layer ? W1  : W0;
    const float* Hw = layer ? Hw1 : Hw0;
    unsigned short* Bt = layer ? Bt1 : Bt0;
    const int k4 = threadIdx.x;                  // use 0..191
    if (k4 < 192){
      float v[4];
      if (n < 768){
        int head = n / 96, f = n % 96;
        const float* base = W + (size_t)head * 768 * 96 + f;
        #pragma unroll
        for (int e = 0; e < 4; ++e) v[e] = base[(size_t)(k4 * 4 + e) * 96];
      } else {
        f32x4 t = *(const f32x4*)(Hw + (size_t)(n - 768) * 768 + k4 * 4);
        #pragma unroll
        for (int e = 0; e < 4; ++e) v[e] = t[e];
      }
      union { unsigned short u[4]; unsigned long long ll; } o;
      #pragma unroll
      for (int e = 0; e < 4; ++e) o.u[e] = f2bf(v[e]);
      ((unsigned long long*)(Bt + (size_t)n * 768))[k4] = o.ll;
    }
  }
}

// ---------------- fused GEMM: C[8192][1536] = A[8192][768] * Bt^T  (BM=128, BN=64, BK=64) ----------------
// ntile<12 -> hT (bf16 [b*8+head][f][node]); else -> glogit bf16 (with Hb pre-added)
// Epilogue stages the C-tile in LDS (reusing the dead staging buffers) -> coalesced 16B stores.
__global__ __launch_bounds__(256, 3)
void gemm_kernel(const unsigned short* __restrict__ A,
                 const unsigned short* __restrict__ Bt,
                 const float* __restrict__ Hb,
                 unsigned short* __restrict__ hT,
                 unsigned short* __restrict__ glogit){
  __shared__ __align__(16) char lds[49152];   // 2 bufs * (A 16KB + B 8KB); reused as epilogue tile
  const int tid  = threadIdx.x;
  const int wid  = tid >> 6;
  const int lane = tid & 63;
  // XCD-aware remap: XCD x gets mtiles [8x,8x+8) x all 24 ntiles (A panel + Bt L2-resident)
  const int orig = blockIdx.x;                 // 0..1535
  const int wgid = (orig & 7) * 192 + (orig >> 3);
  const int mtile = wgid / 24, ntile = wgid % 24;
  const int m0 = mtile * 128, n0 = ntile * 64;
  const int wm = (wid >> 1) * 64, wn = (wid & 1) * 32;
  const int g = lane >> 4, r16 = lane & 15;

  // stage BK=64 tiles: A 1024 chunks (4/thr), B 512 chunks (2/thr), 16B each.
  // linear LDS dest; XOR swizzle on SOURCE: LDS[row][sp] holds k-chunk sp^(row&7)
  auto stage = [&](int kt, char* base){
    #pragma unroll
    for (int c = 0; c < 4; ++c){
      const int ch = c * 256 + tid;
      const int row = ch >> 3, sp = ch & 7;
      const int cj = sp ^ (row & 7);
      gload_lds16(A + (size_t)(m0 + row) * 768 + kt * 64 + cj * 8, base + ch * 16);
    }
    #pragma unroll
    for (int c = 0; c < 2; ++c){
      const int ch = c * 256 + tid;
      const int row = ch >> 3, sp = ch & 7;
      const int cj = sp ^ (row & 7);
      gload_lds16(Bt + (size_t)(n0 + row) * 768 + kt * 64 + cj * 8, base + 16384 + ch * 16);
    }
  };

  f32x4 acc[4][2];
  #pragma unroll
  for (int i = 0; i < 4; ++i)
    #pragma unroll
    for (int j = 0; j < 2; ++j) acc[i][j] = (f32x4){0.f, 0.f, 0.f, 0.f};

  stage(0, lds);
  __syncthreads();

  for (int kt = 0; kt < 12; ++kt){
    const int cur = kt & 1;
    if (kt < 11) stage(kt + 1, lds + (cur ^ 1) * 24576);
    const char* base = lds + cur * 24576;
    bf16x8 af[4][2], bfr[2][2];
    #pragma unroll
    for (int t = 0; t < 4; ++t){
      const int rowA = wm + t * 16 + r16;
      #pragma unroll
      for (int kk = 0; kk < 2; ++kk){
        const int ckk = (kk << 2) | g;
        af[t][kk] = *(const bf16x8*)(base + rowA * 128 + ((ckk ^ (rowA & 7)) << 4));
      }
    }
    #pragma unroll
    for (int nt = 0; nt < 2; ++nt){
      const int rowB = wn + nt * 16 + r16;
      #pragma unroll
      for (int kk = 0; kk < 2; ++kk){
        const int ckk = (kk << 2) | g;
        bfr[nt][kk] = *(const bf16x8*)(base + 16384 + rowB * 128 + ((ckk ^ (rowB & 7)) << 4));
      }
    }
    #pragma unroll
    for (int mt = 0; mt < 4; ++mt)
      #pragma unroll
      for (int nt = 0; nt < 2; ++nt){
        acc[mt][nt] = mfma16(af[mt][0], bfr[nt][0], acc[mt][nt]);
        acc[mt][nt] = mfma16(af[mt][1], bfr[nt][1], acc[mt][nt]);
      }
    __syncthreads();
  }

  if (n0 < 768){
    // ---- h-tile: transpose through LDS [64 n][128 m] bf16 (16KB), chunk-swizzled ----
    #pragma unroll
    for (int mt = 0; mt < 4; ++mt){
      #pragma unroll
      for (int nt = 0; nt < 2; ++nt){
        const int n_local = wn + nt * 16 + r16;
        const int m_base  = wm + mt * 16 + g * 4;
        union { unsigned short u[4]; unsigned long long ll; } pk;
        #pragma unroll
        for (int r = 0; r < 4; ++r) pk.u[r] = f2bf(acc[mt][nt][r]);
        const int byte = m_base * 2;
        const int chunk = byte >> 4, o = byte & 15;
        const int pbyte = n_local * 256 + ((chunk ^ (n_local & 15)) << 4) + o;
        *(unsigned long long*)(lds + pbyte) = pk.ll;
      }
    }
    __syncthreads();
    const int b_ = m0 >> 9, nodebase = m0 & 511;
    #pragma unroll
    for (int it = 0; it < 4; ++it){
      const int ci = it * 256 + tid;              // 0..1023
      const int row = ci >> 4, l = ci & 15;
      const int pbyte = row * 256 + (((l ^ (row & 15))) << 4);
      f32x4 v = *(const f32x4*)(lds + pbyte);
      const int n = n0 + row, head = n / 96, f = n % 96;
      *(f32x4*)(hT + (((size_t)(b_ * 8 + head)) * 96 + f) * 512 + nodebase + l * 8) = v;
    }
  } else {
    // ---- g-tile: direct-layout LDS [128 m][64 n] bf16 (16KB), chunk-swizzled ----
    #pragma unroll
    for (int mt = 0; mt < 4; ++mt){
      #pragma unroll
      for (int nt = 0; nt < 2; ++nt){
        const int n_local = wn + nt * 16 + r16;
        const float hbv = Hb[n0 - 768 + n_local];   // pre-add gate bias (fp32, before bf16 round)
        const int c = n_local >> 3;
        #pragma unroll
        for (int r = 0; r < 4; ++r){
          const int m_local = wm + mt * 16 + g * 4 + r;
          const int pbyte = m_local * 128 + ((c ^ (m_local & 7)) << 4) + (n_local & 7) * 2;
          *(unsigned short*)(lds + pbyte) = f2bf(acc[mt][nt][r] + hbv);
        }
      }
    }
    __syncthreads();
    const int colbase = n0 - 768;
    #pragma unroll
    for (int it = 0; it < 4; ++it){
      const int ci = it * 256 + tid;              // 0..1023
      const int row = ci >> 3, l = ci & 7;
      const int pbyte = row * 128 + ((l ^ (row & 7)) << 4);
      f32x4 v = *(const f32x4*)(lds + pbyte);
      *(f32x4*)(glogit + (size_t)(m0 + row) * 768 + colbase + l * 8) = v;
    }
  }
}

// ---------------- s/d projections from hT (node-contiguous, coalesced) ----------------
// block = bh (128 blocks, 256 thr); thread owns 2 nodes; loop f: 1KB coalesced row loads
__global__ __launch_bounds__(256)
void sd_kernel(const unsigned short* __restrict__ hT, const float* __restrict__ asrc,
               const float* __restrict__ adst, float* __restrict__ s, float* __restrict__ d){
  const int bh = blockIdx.x;          // 0..127
  const int tid = threadIdx.x;
  const int head = bh & 7;
  __shared__ float as_lds[96], ad_lds[96];
  if (tid < 96) as_lds[tid] = asrc[head * 96 + tid];
  else if (tid >= 128 && tid < 224) ad_lds[tid - 128] = adst[head * 96 + tid - 128];
  __syncthreads();

  const unsigned short* hTb = hT + (size_t)bh * 96 * 512 + tid * 2;
  float s0 = 0.f, s1 = 0.f, d0 = 0.f, d1 = 0.f;
  #pragma unroll 8
  for (int f = 0; f < 96; ++f){
    const unsigned int u = *(const unsigned int*)(hTb + (size_t)f * 512);
    const float t0 = fast_tanh(bf2f((unsigned short)(u & 0xffffu)));
    const float t1 = fast_tanh(bf2f((unsigned short)(u >> 16)));
    const float a = as_lds[f], dd = ad_lds[f];
    s0 += t0 * a;  s1 += t1 * a;
    d0 += t0 * dd; d1 += t1 * dd;
  }
  const int o = (bh << 9) + tid * 2;
  *(float2*)(s + o) = make_float2(s0, s1);
  *(float2*)(d + o) = make_float2(d0, d1);
}

// ---------------- fused attention + softmax-PV + gate/ELU/residual/scramble ----------------
__global__ __launch_bounds__(256)
void attn_kernel(const float* __restrict__ s, const float* __restrict__ d,
                 const unsigned int* __restrict__ mask,     // [B][512][16]
                 const unsigned short* __restrict__ hT,     // [BH][F][N] bf16
                 const float* __restrict__ bias,            // [F]
                 const unsigned short* __restrict__ glogit, // [8192][768] bf16 (Hb pre-added)
                 const float* __restrict__ xin,             // [8192][768] fp32 residual
                 float* __restrict__ outf,                  // [8192][768] fp32
                 unsigned short* __restrict__ outb,         // bf16 copy (next-layer A)
                 int write_b){
  const int idx = blockIdx.x;           // bh = idx&127 keeps same-bh blocks on one XCD
  const int bh = idx & 127, ib = idx >> 7;
  const int b  = bh >> 3;
  const int tid = threadIdx.x, wid = tid >> 6, lane = tid & 63;
  const int g = lane >> 4, r16 = lane & 15;
  const int rowbase = ib * 64 + wid * 16;

  __shared__ float d_lds[512];
  __shared__ float bias_lds[96];
  __shared__ __align__(16) char vbuf[2][12288];   // V slices; reused as fp32 out tile [8][768]
  float* att_s = (float*)vbuf;

  const float* dv = d + bh * 512;
  if (tid < 128) ((f32x4*)d_lds)[tid] = ((const f32x4*)dv)[tid];
  if (tid >= 128 && tid < 152) ((f32x4*)bias_lds)[tid - 128] = ((const f32x4*)bias)[tid - 128];

  const unsigned short* hTb = hT + (size_t)bh * 96 * 512;

  auto stage = [&](int p, int bufi){
    #pragma unroll
    for (int ss2 = 0; ss2 < 3; ++ss2){
      const int ch = ss2 * 256 + tid;
      const int row = ch >> 3, slotpos = ch & 7;
      const int cj = slotpos ^ (row & 7);
      gload_lds16(hTb + (size_t)row * 512 + p * 64 + cj * 8, vbuf[bufi] + ch * 16);
    }
  };

  const int i_mine = rowbase + r16;     // this lane's P-row
  const float s_i = s[bh * 512 + i_mine];

  unsigned int mw[16];
  {
    const uint4* mrow = (const uint4*)(mask + ((size_t)b * 512 + i_mine) * 16);
    uint4 a0 = mrow[0], a1 = mrow[1], a2 = mrow[2], a3 = mrow[3];
    mw[0]=a0.x; mw[1]=a0.y; mw[2]=a0.z; mw[3]=a0.w;
    mw[4]=a1.x; mw[5]=a1.y; mw[6]=a1.z; mw[7]=a1.w;
    mw[8]=a2.x; mw[9]=a2.y; mw[10]=a2.z; mw[11]=a2.w;
    mw[12]=a3.x; mw[13]=a3.y; mw[14]=a3.z; mw[15]=a3.w;
  }

  stage(0, 0);
  __syncthreads();   // drains stage(0) + d_lds/bias

  // per-bh UNMASKED max of d: valid upper bound since lrelu is monotone
  float Mx = d_lds[lane];
  #pragma unroll
  for (int t = 1; t < 8; ++t) Mx = fmaxf(Mx, d_lds[t * 64 + lane]);
  #pragma unroll
  for (int o = 32; o > 0; o >>= 1) Mx = fmaxf(Mx, __shfl_xor(Mx, o));
  const float scm = s_i + Mx;
  const float m_i = fmaxf(scm, 0.2f * scm);

  f32x4 acc2[6];
  #pragma unroll
  for (int ft = 0; ft < 6; ++ft) acc2[ft] = (f32x4){0.f, 0.f, 0.f, 0.f};
  float L = 0.f;

  for (int p = 0; p < 8; ++p){
    if (p < 7) stage(p + 1, (p + 1) & 1);
    const char* vb = vbuf[p & 1];
    #pragma unroll
    for (int half = 0; half < 2; ++half){
      const int jt = p * 2 + half;
      const unsigned int w = mw[jt];
      const int j8 = jt * 32 + g * 8;
      f32x4 dA = *(const f32x4*)(d_lds + j8);
      f32x4 dB = *(const f32x4*)(d_lds + j8 + 4);
      u16x8 pa;
      #pragma unroll
      for (int e = 0; e < 4; ++e){
        float sc = s_i + dA[e]; sc = fmaxf(sc, 0.2f * sc);
        float p1 = ((w >> (g * 8 + e)) & 1u) ? __expf(sc - m_i) : 0.f;
        L += p1; pa[e] = f2bf(p1);
        float sc2 = s_i + dB[e]; sc2 = fmaxf(sc2, 0.2f * sc2);
        float p2 = ((w >> (g * 8 + 4 + e)) & 1u) ? __expf(sc2 - m_i) : 0.f;
        L += p2; pa[4 + e] = f2bf(p2);
      }
      const bf16x8 af = __builtin_bit_cast(bf16x8, pa);
      const int slot = ((half * 4 + g) ^ (r16 & 7)) * 16;
      __builtin_amdgcn_s_setprio(1);
      #pragma unroll
      for (int ft = 0; ft < 6; ++ft){
        bf16x8 vf = *(const bf16x8*)(vb + (ft * 16 + r16) * 128 + slot);
        acc2[ft] = mfma16(af, vf, acc2[ft]);
      }
      __builtin_amdgcn_s_setprio(0);
    }
    __syncthreads();
  }

  L += __shfl_xor(L, 16);
  L += __shfl_xor(L, 32);
  const float linv = 1.f / L;
  float lr[4];
  #pragma unroll
  for (int r = 0; r < 4; ++r) lr[r] = __shfl(linv, g * 4 + r);  // linv of row rowbase+g*4+r

  // phase 1: scatter normalized attn (+bias) into LDS out-tile [8][768]
  #pragma unroll
  for (int ft = 0; ft < 6; ++ft){
    const int f = ft * 16 + r16;
    const float bv = bias_lds[f];
    #pragma unroll
    for (int r = 0; r < 4; ++r){
      const int node = rowbase + g * 4 + r;
      att_s[((node >> 3) & 7) * 768 + (node & 7) * 96 + f] = acc2[ft][r] * lr[r] + bv;
    }
  }
  __syncthreads();

  // phase 2: coalesced fused gate/ELU/residual over the contiguous 8-row global range
  const int hh = bh & 7;
  const int bb2 = (hh << 1) | (b >> 3);
  const int mbase = bb2 * 512 + ((b & 7) << 6) + ib * 8;
  const size_t gb4 = (size_t)mbase * 192;     // f32x4 index: mbase*768/4
  #pragma unroll
  for (int sgi = 0; sgi < 6; ++sgi){
    const int ei = sgi * 256 + tid;
    f32x4 a4 = ((const f32x4*)att_s)[ei];
    u16x4 gl = ((const u16x4*)glogit)[gb4 + ei];
    f32x4 xv = ((const f32x4*)xin)[gb4 + ei];
    f32x4 o;
    #pragma unroll
    for (int e = 0; e < 4; ++e){
      const float gate = 1.f / (1.f + __expf(-bf2f(gl[e])));
      const float a = a4[e];
      const float eluv = a > 0.f ? a : (__expf(a) - 1.f);
      o[e] = gate * eluv + (1.f - gate) * xv[e];
    }
    ((f32x4*)outf)[gb4 + ei] = o;
    if (write_b){
      union { unsigned short u[4]; unsigned long long ll; } ob;
      #pragma unroll
      for (int e = 0; e < 4; ++e) ob.u[e] = f2bf(o[e]);
      ((unsigned long long*)outb)[gb4 + ei] = ob.ll;
    }
  }
}

extern "C" void kernel_launch(void* const* d_in, const int* in_sizes, int n_in,
                              void* d_out, int out_size, void* d_ws, size_t ws_size,
                              hipStream_t stream){
  const float* emb   = (const float*)d_in[0];
  const float* adj   = (const float*)d_in[1];
  const float* W0    = (const float*)d_in[3];
  const float* b0    = (const float*)d_in[4];
  const float* asrc0 = (const float*)d_in[5];
  const float* adst0 = (const float*)d_in[6];
  const float* Hw0   = (const float*)d_in[7];
  const float* Hb0   = (const float*)d_in[8];
  const float* W1    = (const float*)d_in[9];
  const float* b1    = (const float*)d_in[10];
  const float* asrc1 = (const float*)d_in[11];
  const float* adst1 = (const float*)d_in[12];
  const float* Hw1   = (const float*)d_in[13];
  const float* Hb1   = (const float*)d_in[14];

  char* ws = (char*)d_ws;
  size_t off = 0;
  auto alloc = [&](size_t bytes){ void* p = ws + off; off += (bytes + 255) & ~(size_t)255; return p; };
  unsigned short* x0b  = (unsigned short*)alloc(8192ull * 768 * 2);  // layer A input (bf16), rewritten by attn L1
  unsigned short* Bt0  = (unsigned short*)alloc(1536ull * 768 * 2);
  unsigned short* Bt1  = (unsigned short*)alloc(1536ull * 768 * 2);
  unsigned short* hT   = (unsigned short*)alloc(8192ull * 768 * 2);
  unsigned short* glogit = (unsigned short*)alloc(8192ull * 768 * 2);
  float* sbuf          = (float*)alloc(65536ull * 4);
  float* dbuf          = (float*)alloc(65536ull * 4);
  float* x1            = (float*)alloc(8192ull * 768 * 4);
  unsigned int* mask   = (unsigned int*)alloc(16ull * 512 * 16 * 4);
  (void)ws_size; (void)in_sizes; (void)n_in; (void)out_size;

  prep_kernel<<<9728, 256, 0, stream>>>(emb, x0b, adj, mask, W0, Hw0, Bt0, W1, Hw1, Bt1);

  // layer 1
  gemm_kernel<<<1536, 256, 0, stream>>>(x0b, Bt0, Hb0, hT, glogit);
  sd_kernel<<<128, 256, 0, stream>>>(hT, asrc0, adst0, sbuf, dbuf);
  attn_kernel<<<1024, 256, 0, stream>>>(sbuf, dbuf, mask, hT, b0, glogit, emb, x1, x0b, 1);

  // layer 2 (x0b now holds bf16 of x1)
  gemm_kernel<<<1536, 256, 0, stream>>>(x0b, Bt1, Hb1, hT, glogit);
  sd_kernel<<<128, 256, 0, stream>>>(hT, asrc1, adst1, sbuf, dbuf);
  attn_kernel<<<1024, 256, 0, stream>>>(sbuf, dbuf, mask, hT, b1, glogit, x1, (float*)d_out, x0b, 0);
}

// Round 7
// 246.721 us; speedup vs baseline: 1.9243x; 1.0062x over previous
//
#include <hip/hip_runtime.h>
#include <cstdint>
#include <cstddef>

// B=16, N=512, D=768, H=8, F=96;  M = B*N = 8192; GEMM N-cols = 768(h) + 768(gate) = 1536; K = 768
typedef __attribute__((ext_vector_type(4))) float f32x4;
typedef __attribute__((ext_vector_type(8))) __bf16 bf16x8;
typedef __attribute__((ext_vector_type(8))) unsigned short u16x8;
typedef __attribute__((ext_vector_type(4))) unsigned short u16x4;

__device__ __forceinline__ unsigned short f2bf(float f){
  unsigned int u = __float_as_uint(f);
  u += 0x7fffu + ((u >> 16) & 1u);          // RNE
  return (unsigned short)(u >> 16);
}
__device__ __forceinline__ float bf2f(unsigned short u){
  return __uint_as_float(((unsigned int)u) << 16);
}
__device__ __forceinline__ float fast_tanh(float x){
  const float e = __expf(2.f * x);          // inf-safe: x>>0 -> 1-0; x<<0 -> 1-2
  return 1.f - 2.f / (e + 1.f);
}

__device__ __forceinline__ void gload_lds16(const void* g, void* l){
  __builtin_amdgcn_global_load_lds((const __attribute__((address_space(1))) void*)g,
                                   (__attribute__((address_space(3))) void*)l, 16, 0, 0);
}

__device__ __forceinline__ f32x4 mfma16(bf16x8 a, bf16x8 b, f32x4 c){
  return __builtin_amdgcn_mfma_f32_16x16x32_bf16(a, b, c, 0, 0, 0);
}

#define SBAR()  { __builtin_amdgcn_sched_barrier(0); __builtin_amdgcn_s_barrier(); __builtin_amdgcn_sched_barrier(0); }

// ---------------- merged prep: emb fp32->bf16 (0..6143) + adj bitmask (6144..6655) + Bt both layers (6656..9727) ----------------
__global__ __launch_bounds__(256) void prep_kernel(const float* __restrict__ in,
                                                   unsigned short* __restrict__ out,
                                                   const float* __restrict__ adj,
                                                   unsigned int* __restrict__ mask,
                                                   const float* __restrict__ W0,
                                                   const float* __restrict__ Hw0,
                                                   unsigned short* __restrict__ Bt0,
                                                   const float* __restrict__ W1,
                                                   const float* __restrict__ Hw1,
                                                   unsigned short* __restrict__ Bt1){
  const int bid = blockIdx.x;
  if (bid < 6144){
    int i = bid * 256 + threadIdx.x;
    f32x4 v = ((const f32x4*)in)[i];
    union { unsigned short u[4]; unsigned long long ll; } o;
    #pragma unroll
    for (int e = 0; e < 4; ++e) o.u[e] = f2bf(v[e]);
    ((unsigned long long*)out)[i] = o.ll;
  } else if (bid < 6656){
    int idx = (bid - 6144) * 256 + threadIdx.x;   // 131072 words
    const float* a = adj + (size_t)idx * 32;
    unsigned int m = 0;
    #pragma unroll
    for (int e = 0; e < 8; ++e){
      f32x4 v = *(const f32x4*)(a + e * 4);
      m |= (v[0] > 0.f ? 1u : 0u) << (e * 4);
      m |= (v[1] > 0.f ? 1u : 0u) << (e * 4 + 1);
      m |= (v[2] > 0.f ? 1u : 0u) << (e * 4 + 2);
      m |= (v[3] > 0.f ? 1u : 0u) << (e * 4 + 3);
    }
    mask[idx] = m;
  } else {
    const int rel = bid - 6656;                  // 0..3071
    const int layer = rel >= 1536;
    const int n = layer ? rel - 1536 : rel;      // 0..1535
    const float* W  = layer ? W1  : W0;
    const float* Hw = layer ? Hw1 : Hw0;
    unsigned short* Bt = layer ? Bt1 : Bt0;
    const int k4 = threadIdx.x;                  // use 0..191
    if (k4 < 192){
      float v[4];
      if (n < 768){
        int head = n / 96, f = n % 96;
        const float* base = W + (size_t)head * 768 * 96 + f;
        #pragma unroll
        for (int e = 0; e < 4; ++e) v[e] = base[(size_t)(k4 * 4 + e) * 96];
      } else {
        f32x4 t = *(const f32x4*)(Hw + (size_t)(n - 768) * 768 + k4 * 4);
        #pragma unroll
        for (int e = 0; e < 4; ++e) v[e] = t[e];
      }
      union { unsigned short u[4]; unsigned long long ll; } o;
      #pragma unroll
      for (int e = 0; e < 4; ++e) o.u[e] = f2bf(v[e]);
      ((unsigned long long*)(Bt + (size_t)n * 768))[k4] = o.ll;
    }
  }
}

// ---------------- fused GEMM: C[8192][1536] = A[8192][768] * Bt^T  (BM=128, BN=64, BK=64) ----------------
// counted-vmcnt pipeline: [vmcnt(6); bar; ds_read+MFMA kt; bar; stage(kt+2)]
__global__ __launch_bounds__(256, 3)
void gemm_kernel(const unsigned short* __restrict__ A,
                 const unsigned short* __restrict__ Bt,
                 const float* __restrict__ Hb,
                 unsigned short* __restrict__ hT,
                 unsigned short* __restrict__ glogit){
  __shared__ __align__(16) char lds[49152];   // 2 bufs * (A 16KB + B 8KB); reused as epilogue tile
  const int tid  = threadIdx.x;
  const int wid  = tid >> 6;
  const int lane = tid & 63;
  // XCD-aware remap: XCD x gets mtiles [8x,8x+8) x all 24 ntiles (A panel + Bt L2-resident)
  const int orig = blockIdx.x;                 // 0..1535
  const int wgid = (orig & 7) * 192 + (orig >> 3);
  const int mtile = wgid / 24, ntile = wgid % 24;
  const int m0 = mtile * 128, n0 = ntile * 64;
  const int wm = (wid >> 1) * 64, wn = (wid & 1) * 32;
  const int g = lane >> 4, r16 = lane & 15;

  // stage BK=64 tiles: A 1024 chunks (4/thr), B 512 chunks (2/thr), 16B each.
  // linear LDS dest; XOR swizzle on SOURCE: LDS[row][sp] holds k-chunk sp^(row&7)
  auto stage = [&](int kt, char* base){
    #pragma unroll
    for (int c = 0; c < 4; ++c){
      const int ch = c * 256 + tid;
      const int row = ch >> 3, sp = ch & 7;
      const int cj = sp ^ (row & 7);
      gload_lds16(A + (size_t)(m0 + row) * 768 + kt * 64 + cj * 8, base + ch * 16);
    }
    #pragma unroll
    for (int c = 0; c < 2; ++c){
      const int ch = c * 256 + tid;
      const int row = ch >> 3, sp = ch & 7;
      const int cj = sp ^ (row & 7);
      gload_lds16(Bt + (size_t)(n0 + row) * 768 + kt * 64 + cj * 8, base + 16384 + ch * 16);
    }
  };

  f32x4 acc[4][2];
  #pragma unroll
  for (int i = 0; i < 4; ++i)
    #pragma unroll
    for (int j = 0; j < 2; ++j) acc[i][j] = (f32x4){0.f, 0.f, 0.f, 0.f};

  stage(0, lds);
  stage(1, lds + 24576);

  for (int kt = 0; kt < 12; ++kt){
    if (kt < 11) { asm volatile("s_waitcnt vmcnt(6)" ::: "memory"); }
    else         { asm volatile("s_waitcnt vmcnt(0)" ::: "memory"); }
    SBAR();
    const char* base = lds + (kt & 1) * 24576;
    bf16x8 af[4][2], bfr[2][2];
    #pragma unroll
    for (int t = 0; t < 4; ++t){
      const int rowA = wm + t * 16 + r16;
      #pragma unroll
      for (int kk = 0; kk < 2; ++kk){
        const int ckk = (kk << 2) | g;
        af[t][kk] = *(const bf16x8*)(base + rowA * 128 + ((ckk ^ (rowA & 7)) << 4));
      }
    }
    #pragma unroll
    for (int nt = 0; nt < 2; ++nt){
      const int rowB = wn + nt * 16 + r16;
      #pragma unroll
      for (int kk = 0; kk < 2; ++kk){
        const int ckk = (kk << 2) | g;
        bfr[nt][kk] = *(const bf16x8*)(base + 16384 + rowB * 128 + ((ckk ^ (rowB & 7)) << 4));
      }
    }
    __builtin_amdgcn_s_setprio(1);
    #pragma unroll
    for (int mt = 0; mt < 4; ++mt)
      #pragma unroll
      for (int nt = 0; nt < 2; ++nt){
        acc[mt][nt] = mfma16(af[mt][0], bfr[nt][0], acc[mt][nt]);
        acc[mt][nt] = mfma16(af[mt][1], bfr[nt][1], acc[mt][nt]);
      }
    __builtin_amdgcn_s_setprio(0);
    SBAR();
    if (kt < 10) stage(kt + 2, lds + (kt & 1) * 24576);
  }

  if (n0 < 768){
    // ---- h-tile: transpose through LDS [64 n][128 m] bf16 (16KB), chunk-swizzled ----
    #pragma unroll
    for (int mt = 0; mt < 4; ++mt){
      #pragma unroll
      for (int nt = 0; nt < 2; ++nt){
        const int n_local = wn + nt * 16 + r16;
        const int m_base  = wm + mt * 16 + g * 4;
        union { unsigned short u[4]; unsigned long long ll; } pk;
        #pragma unroll
        for (int r = 0; r < 4; ++r) pk.u[r] = f2bf(acc[mt][nt][r]);
        const int byte = m_base * 2;
        const int chunk = byte >> 4, o = byte & 15;
        const int pbyte = n_local * 256 + ((chunk ^ (n_local & 15)) << 4) + o;
        *(unsigned long long*)(lds + pbyte) = pk.ll;
      }
    }
    __syncthreads();
    const int b_ = m0 >> 9, nodebase = m0 & 511;
    #pragma unroll
    for (int it = 0; it < 4; ++it){
      const int ci = it * 256 + tid;              // 0..1023
      const int row = ci >> 4, l = ci & 15;
      const int pbyte = row * 256 + (((l ^ (row & 15))) << 4);
      f32x4 v = *(const f32x4*)(lds + pbyte);
      const int n = n0 + row, head = n / 96, f = n % 96;
      *(f32x4*)(hT + (((size_t)(b_ * 8 + head)) * 96 + f) * 512 + nodebase + l * 8) = v;
    }
  } else {
    // ---- g-tile: direct-layout LDS [128 m][64 n] bf16 (16KB), chunk-swizzled ----
    #pragma unroll
    for (int mt = 0; mt < 4; ++mt){
      #pragma unroll
      for (int nt = 0; nt < 2; ++nt){
        const int n_local = wn + nt * 16 + r16;
        const float hbv = Hb[n0 - 768 + n_local];   // pre-add gate bias (fp32, before bf16 round)
        const int c = n_local >> 3;
        #pragma unroll
        for (int r = 0; r < 4; ++r){
          const int m_local = wm + mt * 16 + g * 4 + r;
          const int pbyte = m_local * 128 + ((c ^ (m_local & 7)) << 4) + (n_local & 7) * 2;
          *(unsigned short*)(lds + pbyte) = f2bf(acc[mt][nt][r] + hbv);
        }
      }
    }
    __syncthreads();
    const int colbase = n0 - 768;
    #pragma unroll
    for (int it = 0; it < 4; ++it){
      const int ci = it * 256 + tid;              // 0..1023
      const int row = ci >> 3, l = ci & 7;
      const int pbyte = row * 128 + ((l ^ (row & 7)) << 4);
      f32x4 v = *(const f32x4*)(lds + pbyte);
      *(f32x4*)(glogit + (size_t)(m0 + row) * 768 + colbase + l * 8) = v;
    }
  }
}

// ---------------- s/d projections from hT (node-contiguous, coalesced) ----------------
__global__ __launch_bounds__(256)
void sd_kernel(const unsigned short* __restrict__ hT, const float* __restrict__ asrc,
               const float* __restrict__ adst, float* __restrict__ s, float* __restrict__ d){
  const int bh = blockIdx.x;          // 0..127
  const int tid = threadIdx.x;
  const int head = bh & 7;
  __shared__ float as_lds[96], ad_lds[96];
  if (tid < 96) as_lds[tid] = asrc[head * 96 + tid];
  else if (tid >= 128 && tid < 224) ad_lds[tid - 128] = adst[head * 96 + tid - 128];
  __syncthreads();

  const unsigned short* hTb = hT + (size_t)bh * 96 * 512 + tid * 2;
  float s0 = 0.f, s1 = 0.f, d0 = 0.f, d1 = 0.f;
  #pragma unroll 8
  for (int f = 0; f < 96; ++f){
    const unsigned int u = *(const unsigned int*)(hTb + (size_t)f * 512);
    const float t0 = fast_tanh(bf2f((unsigned short)(u & 0xffffu)));
    const float t1 = fast_tanh(bf2f((unsigned short)(u >> 16)));
    const float a = as_lds[f], dd = ad_lds[f];
    s0 += t0 * a;  s1 += t1 * a;
    d0 += t0 * dd; d1 += t1 * dd;
  }
  const int o = (bh << 9) + tid * 2;
  *(float2*)(s + o) = make_float2(s0, s1);
  *(float2*)(d + o) = make_float2(d0, d1);
}

// ---------------- fused attention + softmax-PV + gate/ELU/residual/scramble ----------------
// 3-buffer counted-vmcnt pipeline: [vmcnt(3); bar; stage(p+2) || compute p]
__global__ __launch_bounds__(256)
void attn_kernel(const float* __restrict__ s, const float* __restrict__ d,
                 const unsigned int* __restrict__ mask,     // [B][512][16]
                 const unsigned short* __restrict__ hT,     // [BH][F][N] bf16
                 const float* __restrict__ bias,            // [F]
                 const unsigned short* __restrict__ glogit, // [8192][768] bf16 (Hb pre-added)
                 const float* __restrict__ xin,             // [8192][768] fp32 residual
                 float* __restrict__ outf,                  // [8192][768] fp32
                 unsigned short* __restrict__ outb,         // bf16 copy (next-layer A)
                 int write_b){
  const int idx = blockIdx.x;           // bh = idx&127 keeps same-bh blocks on one XCD
  const int bh = idx & 127, ib = idx >> 7;
  const int b  = bh >> 3;
  const int tid = threadIdx.x, wid = tid >> 6, lane = tid & 63;
  const int g = lane >> 4, r16 = lane & 15;
  const int rowbase = ib * 64 + wid * 16;

  __shared__ float d_lds[512];
  __shared__ float bias_lds[96];
  __shared__ __align__(16) char vbuf[3][12288];   // V slices; [0..1] reused as fp32 out tile [8][768]
  float* att_s = (float*)vbuf;

  const float* dv = d + bh * 512;
  if (tid < 128) ((f32x4*)d_lds)[tid] = ((const f32x4*)dv)[tid];
  if (tid >= 128 && tid < 152) ((f32x4*)bias_lds)[tid - 128] = ((const f32x4*)bias)[tid - 128];

  const unsigned short* hTb = hT + (size_t)bh * 96 * 512;

  auto stage = [&](int p, int bufi){
    #pragma unroll
    for (int ss2 = 0; ss2 < 3; ++ss2){
      const int ch = ss2 * 256 + tid;
      const int row = ch >> 3, slotpos = ch & 7;
      const int cj = slotpos ^ (row & 7);
      gload_lds16(hTb + (size_t)row * 512 + p * 64 + cj * 8, vbuf[bufi] + ch * 16);
    }
  };

  const int i_mine = rowbase + r16;     // this lane's P-row
  const float s_i = s[bh * 512 + i_mine];

  unsigned int mw[16];
  {
    const uint4* mrow = (const uint4*)(mask + ((size_t)b * 512 + i_mine) * 16);
    uint4 a0 = mrow[0], a1 = mrow[1], a2 = mrow[2], a3 = mrow[3];
    mw[0]=a0.x; mw[1]=a0.y; mw[2]=a0.z; mw[3]=a0.w;
    mw[4]=a1.x; mw[5]=a1.y; mw[6]=a1.z; mw[7]=a1.w;
    mw[8]=a2.x; mw[9]=a2.y; mw[10]=a2.z; mw[11]=a2.w;
    mw[12]=a3.x; mw[13]=a3.y; mw[14]=a3.z; mw[15]=a3.w;
  }

  stage(0, 0);
  stage(1, 1);
  asm volatile("s_waitcnt lgkmcnt(0)" ::: "memory");   // d_lds/bias ds_writes visible before first barrier

  // per-bh UNMASKED max of d: computed after first sync (needs d_lds)
  float m_i;
  f32x4 acc2[6];
  #pragma unroll
  for (int ft = 0; ft < 6; ++ft) acc2[ft] = (f32x4){0.f, 0.f, 0.f, 0.f};
  float L0 = 0.f, L1 = 0.f, L2 = 0.f, L3 = 0.f;

  #pragma unroll
  for (int p = 0; p < 8; ++p){
    if (p < 7) { asm volatile("s_waitcnt vmcnt(3)" ::: "memory"); }
    else       { asm volatile("s_waitcnt vmcnt(0)" ::: "memory"); }
    SBAR();
    if (p == 0){
      float Mx = d_lds[lane];
      #pragma unroll
      for (int t = 1; t < 8; ++t) Mx = fmaxf(Mx, d_lds[t * 64 + lane]);
      #pragma unroll
      for (int o = 32; o > 0; o >>= 1) Mx = fmaxf(Mx, __shfl_xor(Mx, o));
      const float scm = s_i + Mx;
      m_i = fmaxf(scm, 0.2f * scm);    // lrelu monotone => valid upper bound for all rows
    }
    if (p < 6) stage(p + 2, (p + 2) % 3);
    const char* vb = vbuf[p % 3];
    #pragma unroll
    for (int half = 0; half < 2; ++half){
      const int jt = p * 2 + half;
      const unsigned int w = mw[jt];
      const int j8 = jt * 32 + g * 8;
      f32x4 dA = *(const f32x4*)(d_lds + j8);
      f32x4 dB = *(const f32x4*)(d_lds + j8 + 4);
      u16x8 pa;
      #pragma unroll
      for (int e = 0; e < 4; ++e){
        float sc = s_i + dA[e]; sc = fmaxf(sc, 0.2f * sc);
        float p1 = ((w >> (g * 8 + e)) & 1u) ? __expf(sc - m_i) : 0.f;
        float sc2 = s_i + dB[e]; sc2 = fmaxf(sc2, 0.2f * sc2);
        float p2 = ((w >> (g * 8 + 4 + e)) & 1u) ? __expf(sc2 - m_i) : 0.f;
        // 4 independent L-chains (32 deep each) instead of one 128-deep chain
        if (e == 0){ L0 += p1; L0 += p2; } else if (e == 1){ L1 += p1; L1 += p2; }
        else if (e == 2){ L2 += p1; L2 += p2; } else { L3 += p1; L3 += p2; }
        pa[e] = f2bf(p1);
        pa[4 + e] = f2bf(p2);
      }
      const bf16x8 af = __builtin_bit_cast(bf16x8, pa);
      const int slot = ((half * 4 + g) ^ (r16 & 7)) * 16;
      __builtin_amdgcn_s_setprio(1);
      #pragma unroll
      for (int ft = 0; ft < 6; ++ft){
        bf16x8 vf = *(const bf16x8*)(vb + (ft * 16 + r16) * 128 + slot);
        acc2[ft] = mfma16(af, vf, acc2[ft]);
      }
      __builtin_amdgcn_s_setprio(0);
    }
  }
  __syncthreads();   // all compute done; att_s (vbuf[0..1]) free for reuse

  float L = (L0 + L1) + (L2 + L3);
  L += __shfl_xor(L, 16);
  L += __shfl_xor(L, 32);
  const float linv = 1.f / L;
  float lr[4];
  #pragma unroll
  for (int r = 0; r < 4; ++r) lr[r] = __shfl(linv, g * 4 + r);  // linv of row rowbase+g*4+r

  // phase 1: scatter normalized attn (+bias) into LDS out-tile [8][768]
  #pragma unroll
  for (int ft = 0; ft < 6; ++ft){
    const int f = ft * 16 + r16;
    const float bv = bias_lds[f];
    #pragma unroll
    for (int r = 0; r < 4; ++r){
      const int node = rowbase + g * 4 + r;
      att_s[((node >> 3) & 7) * 768 + (node & 7) * 96 + f] = acc2[ft][r] * lr[r] + bv;
    }
  }
  __syncthreads();

  // phase 2: coalesced fused gate/ELU/residual over the contiguous 8-row global range
  const int hh = bh & 7;
  const int bb2 = (hh << 1) | (b >> 3);
  const int mbase = bb2 * 512 + ((b & 7) << 6) + ib * 8;
  const size_t gb4 = (size_t)mbase * 192;     // f32x4 index: mbase*768/4
  #pragma unroll
  for (int sgi = 0; sgi < 6; ++sgi){
    const int ei = sgi * 256 + tid;
    f32x4 a4 = ((const f32x4*)att_s)[ei];
    u16x4 gl = ((const u16x4*)glogit)[gb4 + ei];
    f32x4 xv = ((const f32x4*)xin)[gb4 + ei];
    f32x4 o;
    #pragma unroll
    for (int e = 0; e < 4; ++e){
      const float gate = 1.f / (1.f + __expf(-bf2f(gl[e])));
      const float a = a4[e];
      const float eluv = a > 0.f ? a : (__expf(a) - 1.f);
      o[e] = gate * eluv + (1.f - gate) * xv[e];
    }
    ((f32x4*)outf)[gb4 + ei] = o;
    if (write_b){
      union { unsigned short u[4]; unsigned long long ll; } ob;
      #pragma unroll
      for (int e = 0; e < 4; ++e) ob.u[e] = f2bf(o[e]);
      ((unsigned long long*)outb)[gb4 + ei] = ob.ll;
    }
  }
}

extern "C" void kernel_launch(void* const* d_in, const int* in_sizes, int n_in,
                              void* d_out, int out_size, void* d_ws, size_t ws_size,
                              hipStream_t stream){
  const float* emb   = (const float*)d_in[0];
  const float* adj   = (const float*)d_in[1];
  const float* W0    = (const float*)d_in[3];
  const float* b0    = (const float*)d_in[4];
  const float* asrc0 = (const float*)d_in[5];
  const float* adst0 = (const float*)d_in[6];
  const float* Hw0   = (const float*)d_in[7];
  const float* Hb0   = (const float*)d_in[8];
  const float* W1    = (const float*)d_in[9];
  const float* b1    = (const float*)d_in[10];
  const float* asrc1 = (const float*)d_in[11];
  const float* adst1 = (const float*)d_in[12];
  const float* Hw1   = (const float*)d_in[13];
  const float* Hb1   = (const float*)d_in[14];

  char* ws = (char*)d_ws;
  size_t off = 0;
  auto alloc = [&](size_t bytes){ void* p = ws + off; off += (bytes + 255) & ~(size_t)255; return p; };
  unsigned short* x0b  = (unsigned short*)alloc(8192ull * 768 * 2);  // layer A input (bf16), rewritten by attn L1
  unsigned short* Bt0  = (unsigned short*)alloc(1536ull * 768 * 2);
  unsigned short* Bt1  = (unsigned short*)alloc(1536ull * 768 * 2);
  unsigned short* hT   = (unsigned short*)alloc(8192ull * 768 * 2);
  unsigned short* glogit = (unsigned short*)alloc(8192ull * 768 * 2);
  float* sbuf          = (float*)alloc(65536ull * 4);
  float* dbuf          = (float*)alloc(65536ull * 4);
  float* x1            = (float*)alloc(8192ull * 768 * 4);
  unsigned int* mask   = (unsigned int*)alloc(16ull * 512 * 16 * 4);
  (void)ws_size; (void)in_sizes; (void)n_in; (void)out_size;

  prep_kernel<<<9728, 256, 0, stream>>>(emb, x0b, adj, mask, W0, Hw0, Bt0, W1, Hw1, Bt1);

  // layer 1
  gemm_kernel<<<1536, 256, 0, stream>>>(x0b, Bt0, Hb0, hT, glogit);
  sd_kernel<<<128, 256, 0, stream>>>(hT, asrc0, adst0, sbuf, dbuf);
  attn_kernel<<<1024, 256, 0, stream>>>(sbuf, dbuf, mask, hT, b0, glogit, emb, x1, x0b, 1);

  // layer 2 (x0b now holds bf16 of x1)
  gemm_kernel<<<1536, 256, 0, stream>>>(x0b, Bt1, Hb1, hT, glogit);
  sd_kernel<<<128, 256, 0, stream>>>(hT, asrc1, adst1, sbuf, dbuf);
  attn_kernel<<<1024, 256, 0, stream>>>(sbuf, dbuf, mask, hT, b1, glogit, x1, (float*)d_out, x0b, 0);
}